// Round 1
// 650.619 us; speedup vs baseline: 1.0277x; 1.0277x over previous
//
#include <hip/hip_runtime.h>
#include <hip/hip_bf16.h>
#include <math.h>

// Problem constants
#define DDIM 1024
#define NH   16
#define LTOK 512
#define NBATCH 16

typedef unsigned short u16;
typedef unsigned short u16x8 __attribute__((ext_vector_type(8)));
typedef unsigned short u16x4 __attribute__((ext_vector_type(4)));
typedef __bf16 bf16x8 __attribute__((ext_vector_type(8)));
typedef float f32x4 __attribute__((ext_vector_type(4)));

typedef __attribute__((address_space(1))) void as1_void;
typedef __attribute__((address_space(3))) void as3_void;

__device__ __forceinline__ void llds16(const u16* g, u16* l) {
    // async 16B global->LDS DMA; LDS dest = wave-uniform base + lane*16B
    __builtin_amdgcn_global_load_lds((as1_void*)g, (as3_void*)l, 16, 0, 0);
}

__device__ __forceinline__ float bf2f(u16 u) {
    unsigned v = ((unsigned)u) << 16;
    float f; __builtin_memcpy(&f, &v, 4); return f;
}
__device__ __forceinline__ u16 f2bf(float f) {
    unsigned u; __builtin_memcpy(&u, &f, 4);
    u += 0x7fffu + ((u >> 16) & 1u);   // RNE
    return (u16)(u >> 16);
}

// ---------------------------------------------------------------------------
// Generic MFMA GEMM (projections / vis):  C = act(scale*(A@BT^T)+bias)
// 128x128 tile, BK=32, global_load_lds staging (m97 shape). K>=512 users only.
// ---------------------------------------------------------------------------
__global__ __launch_bounds__(256) void gemm_bt_kernel(
    const u16* __restrict__ A, int lda, long sA1, long sA2,
    const u16* __restrict__ B, int ldb, long sB1, long sB2,
    u16* __restrict__ C, float* __restrict__ Cf, int ldc, long sC1, long sC2,
    int M, int N, int K, int zdiv,
    const float* __restrict__ bias, float scale, int flags)
{
    __shared__ __align__(16) u16 As[128 * 32];
    __shared__ __align__(16) u16 Bs[128 * 32];

    const int z  = blockIdx.y;
    const int zb = z / zdiv, zh = z - zb * zdiv;
    const u16* Ab = A + (long)zb * sA1 + (long)zh * sA2;
    const u16* Bb = B + (long)zb * sB1 + (long)zh * sB2;
    u16*   Cb  = C  ? C  + (long)zb * sC1 + (long)zh * sC2 : nullptr;
    float* Cfb = Cf ? Cf + (long)zb * sC1 + (long)zh * sC2 : nullptr;

    const int tilesN = (N + 127) >> 7;
    const int tm = blockIdx.x / tilesN, tn = blockIdx.x - tm * tilesN;
    const int m0 = tm << 7, n0 = tn << 7;

    const int tid  = threadIdx.x;
    const int lane = tid & 63;
    const int wave = tid >> 6;
    const int wm = (wave & 1) << 6, wn = (wave >> 1) << 6;
    const int quad = lane >> 4, l16 = lane & 15;

    f32x4 acc[4][4];
#pragma unroll
    for (int i = 0; i < 4; i++)
#pragma unroll
        for (int j = 0; j < 4; j++) acc[i][j] = (f32x4){0.f, 0.f, 0.f, 0.f};

    const int lrA = (wave << 5) + (lane >> 2);
    const int lc  = (lane & 3) << 3;
    int ra0 = m0 + lrA;      if (ra0 > M - 1) ra0 = M - 1;
    int ra1 = m0 + lrA + 16; if (ra1 > M - 1) ra1 = M - 1;
    int rb0 = n0 + lrA;      if (rb0 > N - 1) rb0 = N - 1;
    int rb1 = n0 + lrA + 16; if (rb1 > N - 1) rb1 = N - 1;
    const u16* gA0 = Ab + (long)ra0 * lda + lc;
    const u16* gA1 = Ab + (long)ra1 * lda + lc;
    const u16* gB0 = Bb + (long)rb0 * ldb + lc;
    const u16* gB1 = Bb + (long)rb1 * ldb + lc;
    u16* lA0 = As + ((wave << 5) +  0) * 32;
    u16* lA1 = As + ((wave << 5) + 16) * 32;
    u16* lB0 = Bs + ((wave << 5) +  0) * 32;
    u16* lB1 = Bs + ((wave << 5) + 16) * 32;

    for (int k0 = 0; k0 < K; k0 += 32) {
        __syncthreads();
        llds16(gA0 + k0, lA0);
        llds16(gA1 + k0, lA1);
        llds16(gB0 + k0, lB0);
        llds16(gB1 + k0, lB1);
        __syncthreads();

        bf16x8 af[4], bfr[4];
#pragma unroll
        for (int t = 0; t < 4; t++)
            af[t] = *(const bf16x8*)(As + (wm + t * 16 + l16) * 32 + quad * 8);
#pragma unroll
        for (int t = 0; t < 4; t++)
            bfr[t] = *(const bf16x8*)(Bs + (wn + t * 16 + l16) * 32 + quad * 8);
#pragma unroll
        for (int i = 0; i < 4; i++)
#pragma unroll
            for (int j = 0; j < 4; j++)
                acc[i][j] = __builtin_amdgcn_mfma_f32_16x16x32_bf16(
                    af[i], bfr[j], acc[i][j], 0, 0, 0);
    }

#pragma unroll
    for (int j = 0; j < 4; j++) {
        int col  = n0 + wn + j * 16 + l16;
        int colc = col < N ? col : N - 1;
        float bv = bias ? bias[colc] : 0.f;
#pragma unroll
        for (int i = 0; i < 4; i++) {
#pragma unroll
            for (int r = 0; r < 4; r++) {
                int row = m0 + wm + i * 16 + quad * 4 + r;
                float v = acc[i][j][r] * scale + bv;
                if (flags & 1)
                    v = 0.5f * v * (1.f + erff(v * 0.70710678118654752f));
                if (row < M && col < N) {
                    if (Cfb) Cfb[(long)row * ldc + col] = v;
                    else     Cb [(long)row * ldc + col] = f2bf(v);
                }
            }
        }
    }
}

// ---------------------------------------------------------------------------
// Flash attention: O = softmax(scale*Q K^T + mask) V, head dim 64, L = 512.
//   Q,K,O: (b, 512, 1024) bf16, head h at cols h*64..h*64+63
//   VT   : (bh, 64, 512) bf16 (per-head V^T)
// grid (bh=cb*16, qt=8): bh FAST so the 8 qt-blocks of one head land on the
// SAME XCD (256 % 8 == 0) -> K/VT fetched once per XCD, L2-served after.
// Block: 4 waves, 64 q-rows; K-tile(128x64) + VT-tile(64x128) staged in LDS.
//
// SWAPPED-OPERAND layout (T12 analog): S^T = mfma(K_frag, Q_frag) so each
// lane's 32 S values all belong to ONE q-row (q = lane&15).  Softmax is
// fully in-register (exp2 domain, v_cvt_pk_bf16_f32 packing); P^T is
// redistributed to the PV B-fragment with 8 shfl + 4 selects per 32-key
// chunk.  No P LDS buffer -> no 4-way-conflict scalar stores, LDS 53K->35K
// (4 blocks/CU).  PV computes O^T = mfma(VT_frag, PT_frag); V reads are
// byte-identical to the non-swapped version.
// ---------------------------------------------------------------------------
__global__ __launch_bounds__(256, 4) void flash_kernel(
    const u16* __restrict__ Q, const u16* __restrict__ K,
    const u16* __restrict__ VT, u16* __restrict__ O,
    const float* __restrict__ mask, int causal)
{
    __shared__ __align__(16) u16 Ks[128 * 72];    // keys x dims, pad 64->72
    __shared__ __align__(16) u16 Vs[64 * 136];    // dims x keys, pad 128->136
    const int tid  = threadIdx.x;
    const int wave = tid >> 6, lane = tid & 63;
    const int quad = lane >> 4, l16 = lane & 15;
    const int bh = blockIdx.x, qt = blockIdx.y, b = bh >> 4, h = bh & 15;
    const int qbase = qt * 64 + wave * 16;
    const int qrow  = qbase + l16;            // this lane's q row

    // Q fragment (held all kernel).  Used as the MFMA *B* operand:
    // B[k=quad*8+t][n=l16] = Q[qbase+l16][d=quad*8+t]
    const u16* qp = Q + ((long)b * LTOK + qrow) * DDIM + h * 64 + quad * 8;
    bf16x8 aq0 = *(const bf16x8*)(qp);
    bf16x8 aq1 = *(const bf16x8*)(qp + 32);

    f32x4 oacc[4];
#pragma unroll
    for (int jd = 0; jd < 4; jd++) oacc[jd] = (f32x4){0.f, 0.f, 0.f, 0.f};
    float m_st = -3.0e38f;      // running max, log2 domain
    float l_st = 0.f;           // running denom

    // staging maps
    const int krow = tid >> 3,       kcol = (tid & 7) << 3;   // K: 32 rows/issue
    const int vrow = tid >> 2,       vcol = (tid & 3) << 3;   // VT: 64 rows, 4x8 cols/issue
    const u16* gK = K + ((long)b * LTOK + krow) * DDIM + h * 64 + kcol;
    const u16* gV = VT + ((long)bh * 64 + vrow) * LTOK + vcol;

    const float C1    = 0.125f * 1.44269504088896340736f;   // scale*log2(e)
    const float NEGL2 = -10000.0f * 1.44269504088896340736f;

    const int jp    = quad >> 1;                  // P^T parity this quad needs
    const int laneA = ((quad & 1) << 5) | l16;    // src lane (quad 0 or 2)

    const int nkt = causal ? ((qt * 64 + 63) >> 7) + 1 : (LTOK >> 7);
    for (int kt = 0; kt < nkt; kt++) {
        const int k0 = kt << 7;

        __syncthreads();   // prior iteration's Ks/Vs reads complete
#pragma unroll
        for (int i = 0; i < 4; i++)     // K-tile: 128 rows x 64 dims
            *(u16x8*)(Ks + (i * 32 + krow) * 72 + kcol) =
                *(const u16x8*)(gK + (long)(k0 + i * 32) * DDIM);
#pragma unroll
        for (int i = 0; i < 4; i++)     // VT-tile: 64 rows x 128 keys
            *(u16x8*)(Vs + vrow * 136 + i * 32 + vcol) =
                *(const u16x8*)(gV + k0 + i * 32);
        __syncthreads();

        // S^T = K Q^T : C-layout col = l16 = q, row = key = j*16 + quad*4 + r
        f32x4 s[8];
#pragma unroll
        for (int j = 0; j < 8; j++) {
            bf16x8 bk0 = *(const bf16x8*)(Ks + (j * 16 + l16) * 72 + quad * 8);
            bf16x8 bk1 = *(const bf16x8*)(Ks + (j * 16 + l16) * 72 + 32 + quad * 8);
            f32x4 z = (f32x4){0.f, 0.f, 0.f, 0.f};
            z = __builtin_amdgcn_mfma_f32_16x16x32_bf16(bk0, aq0, z, 0, 0, 0);
            s[j] = __builtin_amdgcn_mfma_f32_16x16x32_bf16(bk1, aq1, z, 0, 0, 0);
        }

        // scale (+mask) in log2 domain; per-lane tile max over this lane's 32 keys
        float tm0 = -3.0e38f, tm1 = -3.0e38f, tm2 = -3.0e38f, tm3 = -3.0e38f;
#pragma unroll
        for (int j = 0; j < 8; j++) {
            if (causal) {
                f32x4 m4 = *(const f32x4*)(mask + (long)b * LTOK + k0 + j * 16 + quad * 4);
#pragma unroll
                for (int r = 0; r < 4; r++) {
                    int key = k0 + j * 16 + quad * 4 + r;
                    // additive mask: (1-mk)*NEG*log2e, mk = key<=q ? mask : 0
                    float ad = (key <= qrow) ? fmaf(m4[r], -NEGL2, NEGL2) : NEGL2;
                    s[j][r] = fmaf(s[j][r], C1, ad);
                }
            } else {
#pragma unroll
                for (int r = 0; r < 4; r++) s[j][r] *= C1;
            }
            tm0 = fmaxf(tm0, s[j][0]); tm1 = fmaxf(tm1, s[j][1]);
            tm2 = fmaxf(tm2, s[j][2]); tm3 = fmaxf(tm3, s[j][3]);
        }
        float tmax = fmaxf(fmaxf(tm0, tm1), fmaxf(tm2, tm3));
        // combine across the 4 quads holding the same q-row
        tmax = fmaxf(tmax, __shfl_xor(tmax, 16));
        tmax = fmaxf(tmax, __shfl_xor(tmax, 32));

        float mnew  = fmaxf(m_st, tmax);
        float alpha = __builtin_amdgcn_exp2f(m_st - mnew);
        m_st = mnew;

        // P = exp2(S2 - m); pack to bf16 pairs in-register
        float rs0 = 0.f, rs1 = 0.f, rs2 = 0.f, rs3 = 0.f;
        unsigned pk[8][2];
#pragma unroll
        for (int j = 0; j < 8; j++) {
            float p0 = __builtin_amdgcn_exp2f(s[j][0] - mnew);
            float p1 = __builtin_amdgcn_exp2f(s[j][1] - mnew);
            float p2 = __builtin_amdgcn_exp2f(s[j][2] - mnew);
            float p3 = __builtin_amdgcn_exp2f(s[j][3] - mnew);
            rs0 += p0; rs1 += p1; rs2 += p2; rs3 += p3;
            asm("v_cvt_pk_bf16_f32 %0, %1, %2" : "=v"(pk[j][0]) : "v"(p0), "v"(p1));
            asm("v_cvt_pk_bf16_f32 %0, %1, %2" : "=v"(pk[j][1]) : "v"(p2), "v"(p3));
        }
        float rsum = (rs0 + rs1) + (rs2 + rs3);
        rsum += __shfl_xor(rsum, 16);
        rsum += __shfl_xor(rsum, 32);
        l_st = l_st * alpha + rsum;

#pragma unroll
        for (int jd = 0; jd < 4; jd++) oacc[jd] *= alpha;

        // O^T += V^T P^T.  B-frag needs P^T[key=32kk+8*quad+t][q=l16]:
        // gather from source quads 2*(quad&1) and +1, j-parity = quad>>1.
#pragma unroll
        for (int kk = 0; kk < 4; kk++) {
            unsigned e0 = __shfl(pk[2 * kk][0],     laneA);
            unsigned e1 = __shfl(pk[2 * kk][1],     laneA);
            unsigned o0 = __shfl(pk[2 * kk + 1][0], laneA);
            unsigned o1 = __shfl(pk[2 * kk + 1][1], laneA);
            unsigned w0 = jp ? o0 : e0;
            unsigned w1 = jp ? o1 : e1;
            e0 = __shfl(pk[2 * kk][0],     laneA + 16);
            e1 = __shfl(pk[2 * kk][1],     laneA + 16);
            o0 = __shfl(pk[2 * kk + 1][0], laneA + 16);
            o1 = __shfl(pk[2 * kk + 1][1], laneA + 16);
            unsigned w2 = jp ? o0 : e0;
            unsigned w3 = jp ? o1 : e1;
            unsigned wv[4] = {w0, w1, w2, w3};
            bf16x8 bp; __builtin_memcpy(&bp, wv, 16);
#pragma unroll
            for (int jd = 0; jd < 4; jd++) {
                bf16x8 av = *(const bf16x8*)(Vs + (jd * 16 + l16) * 136
                                                + kk * 32 + quad * 8);
                oacc[jd] = __builtin_amdgcn_mfma_f32_16x16x32_bf16(av, bp, oacc[jd], 0, 0, 0);
            }
        }
    }

    // O^T element (d = jd*16 + quad*4 + r, q = l16): 4 consecutive cols/lane
    float linv = 1.f / l_st;
    long obase = ((long)b * LTOK + qrow) * DDIM + h * 64;
#pragma unroll
    for (int jd = 0; jd < 4; jd++) {
        u16x4 ov;
#pragma unroll
        for (int r = 0; r < 4; r++) ov[r] = f2bf(oacc[jd][r] * linv);
        *(u16x4*)(O + obase + jd * 16 + quad * 4) = ov;
    }
}

// out = LayerNorm(a + b) * g + beta.  a: bf16.  b: bf16 unless b32 (fp32).
// Output: bf16 (o) unless of != nullptr (fp32).  Row length 1024.
__global__ __launch_bounds__(256) void add_ln_kernel(
    const u16* __restrict__ a, const u16* __restrict__ b,
    const float* __restrict__ b32,
    const float* __restrict__ g, const float* __restrict__ bt,
    u16* __restrict__ o, float* __restrict__ of)
{
    long row = blockIdx.x;
    int tid = threadIdx.x;
    __shared__ float red[4];
    const u16* ar = a + row * DDIM;
    float xv[4]; float s = 0.f;
#pragma unroll
    for (int i = 0; i < 4; i++) {
        int c = tid + 256 * i;
        float sum = bf2f(ar[c]) + (b32 ? b32[row * DDIM + c] : bf2f(b[row * DDIM + c]));
        xv[i] = fminf(fmaxf(sum, -1.0e18f), 1.0e18f);
        s += xv[i];
    }
#pragma unroll
    for (int ofs = 32; ofs >= 1; ofs >>= 1) s += __shfl_xor(s, ofs);
    int wave = tid >> 6, lane = tid & 63;
    if (lane == 0) red[wave] = s;
    __syncthreads();
    float mu = (red[0] + red[1] + red[2] + red[3]) * (1.f / 1024.f);
    __syncthreads();
    float v = 0.f;
#pragma unroll
    for (int i = 0; i < 4; i++) { float d = xv[i] - mu; v += d * d; }
#pragma unroll
    for (int ofs = 32; ofs >= 1; ofs >>= 1) v += __shfl_xor(v, ofs);
    if (lane == 0) red[wave] = v;
    __syncthreads();
    float var = (red[0] + red[1] + red[2] + red[3]) * (1.f / 1024.f);
    float inv = rsqrtf(var + 1e-6f);
#pragma unroll
    for (int i = 0; i < 4; i++) {
        int c = tid + 256 * i;
        float r = (xv[i] - mu) * inv * g[c] + bt[c];
        if (of) of[row * DDIM + c] = r;
        else    o [row * DDIM + c] = f2bf(r);
    }
}

// fp32 -> bf16 conversion, 8 elements/thread.
__global__ __launch_bounds__(256) void cvt_kernel(
    const float* __restrict__ src, u16* __restrict__ dst)
{
    long i = ((long)blockIdx.x * 256 + threadIdx.x) * 8;
    u16x8 o;
#pragma unroll
    for (int j = 0; j < 8; j++) o[j] = f2bf(src[i + j]);
    *(u16x8*)(dst + i) = o;
}

// Transpose+cvt the 8 fp32 weight matrices (1024x1024): WT[n][k] = bf16(W[k][n])
__global__ __launch_bounds__(256) void wt_kernel(
    const float* w0, const float* w1, const float* w2, const float* w3,
    const float* w4, const float* w5, const float* w6, const float* w7,
    u16* __restrict__ wt)
{
    const float* srcs[8] = {w0, w1, w2, w3, w4, w5, w6, w7};
    const float* w = srcs[blockIdx.z];
    u16* o = wt + (long)blockIdx.z * DDIM * DDIM;
    __shared__ u16 t[32][33];
    int tx = threadIdx.x & 31, ty = threadIdx.x >> 5;
    int c0 = blockIdx.x << 5, r0 = blockIdx.y << 5;
#pragma unroll
    for (int i = 0; i < 4; i++)
        t[ty + 8 * i][tx] = f2bf(w[(long)(r0 + ty + 8 * i) * DDIM + c0 + tx]);
    __syncthreads();
#pragma unroll
    for (int i = 0; i < 4; i++)
        o[(long)(c0 + ty + 8 * i) * DDIM + r0 + tx] = t[tx][ty + 8 * i];
}

// vt[(b*NH+h)*64 + dd][k] = v[b*LTOK + k][h*64 + dd]   (per-head V transpose)
__global__ __launch_bounds__(256) void vtrans_kernel(
    const u16* __restrict__ v, u16* __restrict__ vt)
{
    int bh = blockIdx.y; int b = bh >> 4, h = bh & 15;
    int k0 = blockIdx.x << 5;
    __shared__ __align__(16) u16 t[32 * 72];
    int kk = threadIdx.x >> 3, c = (threadIdx.x & 7) << 3;
    u16x8 val = *(const u16x8*)(v + ((long)b * LTOK + k0 + kk) * DDIM + h * 64 + c);
    *(u16x8*)(t + kk * 72 + c) = val;
    __syncthreads();
    int dd = threadIdx.x >> 2, k2 = (threadIdx.x & 3) << 3;
    u16x8 o;
#pragma unroll
    for (int j = 0; j < 8; j++) o[j] = t[(k2 + j) * 72 + dd];
    *(u16x8*)(vt + ((long)bh * 64 + dd) * LTOK + k0 + k2) = o;
}

extern "C" void kernel_launch(void* const* d_in, const int* in_sizes, int n_in,
                              void* d_out, int out_size, void* d_ws, size_t ws_size,
                              hipStream_t stream)
{
    const float* x     = (const float*)d_in[0];
    const float* dmsk  = (const float*)d_in[1];
    const float* enc   = (const float*)d_in[2];
    const float* sa_wq = (const float*)d_in[3];  const float* sa_bq = (const float*)d_in[4];
    const float* sa_wk = (const float*)d_in[5];  const float* sa_bk = (const float*)d_in[6];
    const float* sa_wv = (const float*)d_in[7];  const float* sa_bv = (const float*)d_in[8];
    const float* n1_g  = (const float*)d_in[9];  const float* n1_b  = (const float*)d_in[10];
    const float* ca_wq = (const float*)d_in[11]; const float* ca_bq = (const float*)d_in[12];
    const float* ca_wk = (const float*)d_in[13]; const float* ca_bk = (const float*)d_in[14];
    const float* ca_wv = (const float*)d_in[15]; const float* ca_bv = (const float*)d_in[16];
    const float* n2_g  = (const float*)d_in[17]; const float* n2_b  = (const float*)d_in[18];
    const float* int_w = (const float*)d_in[19]; const float* int_b = (const float*)d_in[20];
    const float* out_w = (const float*)d_in[21]; const float* out_b = (const float*)d_in[22];
    const float* out_g = (const float*)d_in[23]; const float* out_bt= (const float*)d_in[24];

    float* outp = (float*)d_out;
    float* visp = outp + (long)NBATCH * LTOK * DDIM;   // attention_vis (fp32)

    // --- workspace: chunk over batches; 7 act buffers / batch + WT ---
    const size_t WTB  = (size_t)8 * DDIM * DDIM * 2;            // 16 MiB
    const size_t BUF1 = (size_t)LTOK * DDIM * 2;                // 1 MiB / batch
    int cb = 16;
    while (cb > 1 && WTB + (size_t)cb * 7 * BUF1 + 8192 > ws_size)
        cb >>= 1;

    char* ws = (char*)d_ws;
    size_t off = 0;
    auto alloc = [&](size_t bytes) -> u16* {
        u16* p = (u16*)(ws + off);
        off += (bytes + 255) & ~(size_t)255;
        return p;
    };
    u16* Bq  = alloc((size_t)cb * BUF1);
    u16* Bk  = alloc((size_t)cb * BUF1);
    u16* Bv  = alloc((size_t)cb * BUF1);
    u16* Bt  = alloc((size_t)cb * BUF1);
    u16* Bt2 = alloc((size_t)cb * BUF1);
    u16* Xb  = alloc((size_t)cb * BUF1);
    u16* Eb  = alloc((size_t)cb * BUF1);
    u16* WT  = alloc(WTB);
    // no memset needed: every region fully written before read.

    u16* Wsaq = WT + 0L * DDIM * DDIM; u16* Wsak = WT + 1L * DDIM * DDIM;
    u16* Wsav = WT + 2L * DDIM * DDIM; u16* Wcaq = WT + 3L * DDIM * DDIM;
    u16* Wcak = WT + 4L * DDIM * DDIM; u16* Wcav = WT + 5L * DDIM * DDIM;
    u16* Wint = WT + 6L * DDIM * DDIM; u16* Wout = WT + 7L * DDIM * DDIM;

    auto gemm = [&](const u16* A, int lda, long sA1, long sA2,
                    const u16* B, int ldb, long sB1, long sB2,
                    u16* C, float* Cf, int ldc, long sC1, long sC2,
                    int M, int N, int K, int Z, int zdiv,
                    const float* bias, float scale, int flags) {
        int tM = (M + 127) / 128, tN = (N + 127) / 128;
        gemm_bt_kernel<<<dim3(tM * tN, Z), dim3(256), 0, stream>>>(
            A, lda, sA1, sA2, B, ldb, sB1, sB2, C, Cf, ldc, sC1, sC2,
            M, N, K, zdiv, bias, scale, flags);
    };

    const long SLD = (long)LTOK * DDIM;       // per-batch row-block stride
    const long SSC = (long)LTOK * LTOK;       // vis elems per batch

    // 0) weight transposes + bf16 cvt (once per call)
    wt_kernel<<<dim3(32, 32, 8), dim3(256), 0, stream>>>(
        sa_wq, sa_wk, sa_wv, ca_wq, ca_wk, ca_wv, int_w, out_w, WT);

    for (int b0 = 0; b0 < NBATCH; b0 += cb) {
        const float* xc = x   + (long)b0 * SLD;
        const float* ec = enc + (long)b0 * SLD;
        const int M = cb * LTOK;
        const int Z = cb * NH;
        const int cvtg = (int)(((long)M * DDIM) / (256 * 8));

        // a) fp32 -> bf16 activation copies
        cvt_kernel<<<dim3(cvtg), dim3(256), 0, stream>>>(xc, Xb);
        cvt_kernel<<<dim3(cvtg), dim3(256), 0, stream>>>(ec, Eb);

        // 1) self-attn q,k,v projections
        gemm(Xb, DDIM, 0, 0, Wsaq, DDIM, 0, 0, Bq, nullptr, DDIM, 0, 0, M, DDIM, DDIM, 1, 1, sa_bq, 1.f, 0);
        gemm(Xb, DDIM, 0, 0, Wsak, DDIM, 0, 0, Bk, nullptr, DDIM, 0, 0, M, DDIM, DDIM, 1, 1, sa_bk, 1.f, 0);
        gemm(Xb, DDIM, 0, 0, Wsav, DDIM, 0, 0, Bv, nullptr, DDIM, 0, 0, M, DDIM, DDIM, 1, 1, sa_bv, 1.f, 0);
        vtrans_kernel<<<dim3(16, Z), dim3(256), 0, stream>>>(Bv, Bt);

        // 2) self-attention (flash, causal+padding), ctx -> Bv
        flash_kernel<<<dim3(Z, 8), dim3(256), 0, stream>>>(
            Bq, Bk, Bt, Bv, dmsk + (long)b0 * LTOK, 1);

        // 3) h = LN(ctx + x_fp32) -> Bq
        add_ln_kernel<<<dim3(M), dim3(256), 0, stream>>>(
            Bv, nullptr, xc, n1_g, n1_b, Bq, nullptr);

        // 4) cross projections: cq->Bk, ck->Bv, cv->Bt
        gemm(Bq, DDIM, 0, 0, Wcaq, DDIM, 0, 0, Bk, nullptr, DDIM, 0, 0, M, DDIM, DDIM, 1, 1, ca_bq, 1.f, 0);
        gemm(Eb, DDIM, 0, 0, Wcak, DDIM, 0, 0, Bv, nullptr, DDIM, 0, 0, M, DDIM, DDIM, 1, 1, ca_bk, 1.f, 0);
        gemm(Eb, DDIM, 0, 0, Wcav, DDIM, 0, 0, Bt, nullptr, DDIM, 0, 0, M, DDIM, DDIM, 1, 1, ca_bv, 1.f, 0);

        // 5) attention_vis = (cq @ ck^T) / 128  -> fp32 d_out
        gemm(Bk, DDIM, SLD, 0, Bv, DDIM, SLD, 0,
             nullptr, visp + (long)b0 * SSC, LTOK, SSC, 0,
             LTOK, LTOK, DDIM, cb, 1, nullptr, 1.f / 128.f, 0);

        // 6) cross-attention (flash, no mask): vt(cv)->Bt2; ctx -> Bt
        vtrans_kernel<<<dim3(16, Z), dim3(256), 0, stream>>>(Bt, Bt2);
        flash_kernel<<<dim3(Z, 8), dim3(256), 0, stream>>>(
            Bk, Bv, Bt2, Bt, nullptr, 0);

        // 7) h2 = LN(h + cactx) -> Bv
        add_ln_kernel<<<dim3(M), dim3(256), 0, stream>>>(
            Bq, Bt, nullptr, n2_g, n2_b, Bv, nullptr);

        // 8) inter = gelu(h2 @ int_w + int_b) -> Bk
        gemm(Bv, DDIM, 0, 0, Wint, DDIM, 0, 0, Bk, nullptr, DDIM, 0, 0, M, DDIM, DDIM, 1, 1, int_b, 1.f, 1);
        // 9) G = inter @ out_w + out_b -> Bt
        gemm(Bk, DDIM, 0, 0, Wout, DDIM, 0, 0, Bt, nullptr, DDIM, 0, 0, M, DDIM, DDIM, 1, 1, out_b, 1.f, 0);
        // 10) out = LN(G + inter) -> fp32 d_out
        add_ln_kernel<<<dim3(M), dim3(256), 0, stream>>>(
            Bt, Bk, nullptr, out_g, out_bt, nullptr, outp + (long)b0 * SLD);
    }
}

// Round 2
// 616.195 us; speedup vs baseline: 1.0851x; 1.0559x over previous
//
#include <hip/hip_runtime.h>
#include <hip/hip_bf16.h>
#include <math.h>

// Problem constants
#define DDIM 1024
#define NH   16
#define LTOK 512
#define NBATCH 16

typedef unsigned short u16;
typedef unsigned short u16x8 __attribute__((ext_vector_type(8)));
typedef unsigned short u16x4 __attribute__((ext_vector_type(4)));
typedef __bf16 bf16x8 __attribute__((ext_vector_type(8)));
typedef float f32x4 __attribute__((ext_vector_type(4)));

typedef __attribute__((address_space(1))) void as1_void;
typedef __attribute__((address_space(3))) void as3_void;

__device__ __forceinline__ void llds16(const u16* g, u16* l) {
    // async 16B global->LDS DMA; LDS dest = wave-uniform base + lane*16B
    __builtin_amdgcn_global_load_lds((as1_void*)g, (as3_void*)l, 16, 0, 0);
}

__device__ __forceinline__ float bf2f(u16 u) {
    unsigned v = ((unsigned)u) << 16;
    float f; __builtin_memcpy(&f, &v, 4); return f;
}
__device__ __forceinline__ u16 f2bf(float f) {
    unsigned u; __builtin_memcpy(&u, &f, 4);
    u += 0x7fffu + ((u >> 16) & 1u);   // RNE
    return (u16)(u >> 16);
}

// ---------------------------------------------------------------------------
// Generic MFMA GEMM (projections / vis):  C = act(scale*(A@BT^T)+bias)
// 128x128 tile, BK=32, global_load_lds staging (m97 shape). K>=512 users only.
// XCD swizzle (T1): when tilesM%8==0, group all tilesN blocks of one A-panel
// onto one XCD (dispatch round-robins linear wg id across the 8 XCDs).
// ---------------------------------------------------------------------------
__global__ __launch_bounds__(256) void gemm_bt_kernel(
    const u16* __restrict__ A, int lda, long sA1, long sA2,
    const u16* __restrict__ B, int ldb, long sB1, long sB2,
    u16* __restrict__ C, float* __restrict__ Cf, int ldc, long sC1, long sC2,
    int M, int N, int K, int zdiv,
    const float* __restrict__ bias, float scale, int flags)
{
    __shared__ __align__(16) u16 As[128 * 32];
    __shared__ __align__(16) u16 Bs[128 * 32];

    const int z  = blockIdx.y;
    const int zb = z / zdiv, zh = z - zb * zdiv;
    const u16* Ab = A + (long)zb * sA1 + (long)zh * sA2;
    const u16* Bb = B + (long)zb * sB1 + (long)zh * sB2;
    u16*   Cb  = C  ? C  + (long)zb * sC1 + (long)zh * sC2 : nullptr;
    float* Cfb = Cf ? Cf + (long)zb * sC1 + (long)zh * sC2 : nullptr;

    const int tilesN = (N + 127) >> 7;
    const int tilesM = (M + 127) >> 7;
    int tm, tn;
    if ((tilesM & 7) == 0) {
        // bijective XCD-grouping swizzle: tm % 8 == linear-wg % 8
        const int xcd = blockIdx.x & 7, idx = blockIdx.x >> 3;
        const int mg  = tilesM >> 3;
        tm = ((idx % mg) << 3) | xcd;
        tn = idx / mg;
    } else {
        tm = blockIdx.x / tilesN;
        tn = blockIdx.x - tm * tilesN;
    }
    const int m0 = tm << 7, n0 = tn << 7;

    const int tid  = threadIdx.x;
    const int lane = tid & 63;
    const int wave = tid >> 6;
    const int wm = (wave & 1) << 6, wn = (wave >> 1) << 6;
    const int quad = lane >> 4, l16 = lane & 15;

    f32x4 acc[4][4];
#pragma unroll
    for (int i = 0; i < 4; i++)
#pragma unroll
        for (int j = 0; j < 4; j++) acc[i][j] = (f32x4){0.f, 0.f, 0.f, 0.f};

    const int lrA = (wave << 5) + (lane >> 2);
    const int lc  = (lane & 3) << 3;
    int ra0 = m0 + lrA;      if (ra0 > M - 1) ra0 = M - 1;
    int ra1 = m0 + lrA + 16; if (ra1 > M - 1) ra1 = M - 1;
    int rb0 = n0 + lrA;      if (rb0 > N - 1) rb0 = N - 1;
    int rb1 = n0 + lrA + 16; if (rb1 > N - 1) rb1 = N - 1;
    const u16* gA0 = Ab + (long)ra0 * lda + lc;
    const u16* gA1 = Ab + (long)ra1 * lda + lc;
    const u16* gB0 = Bb + (long)rb0 * ldb + lc;
    const u16* gB1 = Bb + (long)rb1 * ldb + lc;
    u16* lA0 = As + ((wave << 5) +  0) * 32;
    u16* lA1 = As + ((wave << 5) + 16) * 32;
    u16* lB0 = Bs + ((wave << 5) +  0) * 32;
    u16* lB1 = Bs + ((wave << 5) + 16) * 32;

    for (int k0 = 0; k0 < K; k0 += 32) {
        __syncthreads();
        llds16(gA0 + k0, lA0);
        llds16(gA1 + k0, lA1);
        llds16(gB0 + k0, lB0);
        llds16(gB1 + k0, lB1);
        __syncthreads();

        bf16x8 af[4], bfr[4];
#pragma unroll
        for (int t = 0; t < 4; t++)
            af[t] = *(const bf16x8*)(As + (wm + t * 16 + l16) * 32 + quad * 8);
#pragma unroll
        for (int t = 0; t < 4; t++)
            bfr[t] = *(const bf16x8*)(Bs + (wn + t * 16 + l16) * 32 + quad * 8);
#pragma unroll
        for (int i = 0; i < 4; i++)
#pragma unroll
            for (int j = 0; j < 4; j++)
                acc[i][j] = __builtin_amdgcn_mfma_f32_16x16x32_bf16(
                    af[i], bfr[j], acc[i][j], 0, 0, 0);
    }

#pragma unroll
    for (int j = 0; j < 4; j++) {
        int col  = n0 + wn + j * 16 + l16;
        int colc = col < N ? col : N - 1;
        float bv = bias ? bias[colc] : 0.f;
#pragma unroll
        for (int i = 0; i < 4; i++) {
#pragma unroll
            for (int r = 0; r < 4; r++) {
                int row = m0 + wm + i * 16 + quad * 4 + r;
                float v = acc[i][j][r] * scale + bv;
                if (flags & 1)
                    v = 0.5f * v * (1.f + erff(v * 0.70710678118654752f));
                if (row < M && col < N) {
                    if (Cfb) Cfb[(long)row * ldc + col] = v;
                    else     Cb [(long)row * ldc + col] = f2bf(v);
                }
            }
        }
    }
}

// ---------------------------------------------------------------------------
// Flash attention: O = softmax(scale*Q K^T + mask) V, head dim 64, L = 512.
//   Q,K,O: (b, 512, 1024) bf16, head h at cols h*64..h*64+63
//   VT   : (bh, 64, 512) bf16 (per-head V^T)
// grid (bh=cb*16, qt=8): bh FAST so the 8 qt-blocks of one head land on the
// SAME XCD (256 % 8 == 0) -> K/VT fetched once per XCD, L2-served after.
// Block: 4 waves, 64 q-rows; K-tile(128x64) + VT-tile(64x128) staged in LDS.
//
// Swapped-operand S^T = mfma(K,Q): each lane's 32 S values belong to ONE
// q-row (q = l16); softmax fully in-register (exp2 domain, v_cvt_pk_bf16).
// ZERO-SHUFFLE PV: the key axis of the PV sum is permuted by
//   sigma(kk,quad,t) = 32kk + 16*(t>>2) + 4*quad + (t&3)
// so the B-fragment of lane (quad,l16) is exactly its own pk[2kk..2kk+1]
// registers (no ds_bpermute), and V's A-fragment is read with the same
// sigma as two b64 LDS loads (bank-balanced).  T14 async-STAGE: next
// tile's K/V global loads issue before compute, LDS write after barrier.
// ---------------------------------------------------------------------------
__global__ __launch_bounds__(256, 4) void flash_kernel(
    const u16* __restrict__ Q, const u16* __restrict__ K,
    const u16* __restrict__ VT, u16* __restrict__ O,
    const float* __restrict__ mask, int causal)
{
    __shared__ __align__(16) u16 Ks[128 * 72];    // keys x dims, pad 64->72
    __shared__ __align__(16) u16 Vs[64 * 136];    // dims x keys, pad 128->136
    const int tid  = threadIdx.x;
    const int wave = tid >> 6, lane = tid & 63;
    const int quad = lane >> 4, l16 = lane & 15;
    const int bh = blockIdx.x, qt = blockIdx.y, b = bh >> 4, h = bh & 15;
    const int qbase = qt * 64 + wave * 16;
    const int qrow  = qbase + l16;            // this lane's q row

    // Q fragment (held all kernel).  Used as the MFMA *B* operand:
    // B[k=quad*8+t][n=l16] = Q[qbase+l16][d=quad*8+t]
    const u16* qp = Q + ((long)b * LTOK + qrow) * DDIM + h * 64 + quad * 8;
    bf16x8 aq0 = *(const bf16x8*)(qp);
    bf16x8 aq1 = *(const bf16x8*)(qp + 32);

    f32x4 oacc[4];
#pragma unroll
    for (int jd = 0; jd < 4; jd++) oacc[jd] = (f32x4){0.f, 0.f, 0.f, 0.f};
    float m_st = -3.0e38f;      // running max, log2 domain
    float l_st = 0.f;           // running denom

    // staging maps
    const int krow = tid >> 3,       kcol = (tid & 7) << 3;   // K: 32 rows/issue
    const int vrow = tid >> 2,       vcol = (tid & 3) << 3;   // VT: 64 rows, 4x8 cols/issue
    const u16* gK = K + ((long)b * LTOK + krow) * DDIM + h * 64 + kcol;
    const u16* gV = VT + ((long)bh * 64 + vrow) * LTOK + vcol;

    const float C1    = 0.125f * 1.44269504088896340736f;   // scale*log2(e)
    const float NEGL2 = -10000.0f * 1.44269504088896340736f;

    const int nkt = causal ? ((qt * 64 + 63) >> 7) + 1 : (LTOK >> 7);

    // ---- prologue: stage tile 0 ----
    u16x8 KR[4], VR[4];
#pragma unroll
    for (int i = 0; i < 4; i++) KR[i] = *(const u16x8*)(gK + (long)(i * 32) * DDIM);
#pragma unroll
    for (int i = 0; i < 4; i++) VR[i] = *(const u16x8*)(gV + i * 32);
#pragma unroll
    for (int i = 0; i < 4; i++)
        *(u16x8*)(Ks + (i * 32 + krow) * 72 + kcol) = KR[i];
#pragma unroll
    for (int i = 0; i < 4; i++)
        *(u16x8*)(Vs + vrow * 136 + i * 32 + vcol) = VR[i];
    __syncthreads();

    for (int kt = 0; kt < nkt; kt++) {
        const int k0 = kt << 7;
        const bool more = (kt + 1 < nkt);     // block-uniform

        // T14: issue next tile's global loads now; write to LDS after compute
        if (more) {
            const int kn = k0 + 128;
#pragma unroll
            for (int i = 0; i < 4; i++)
                KR[i] = *(const u16x8*)(gK + (long)(kn + i * 32) * DDIM);
#pragma unroll
            for (int i = 0; i < 4; i++)
                VR[i] = *(const u16x8*)(gV + kn + i * 32);
        }

        // S^T = K Q^T : C-layout col = l16 = q, row = key = j*16 + quad*4 + r
        f32x4 s[8];
#pragma unroll
        for (int j = 0; j < 8; j++) {
            bf16x8 bk0 = *(const bf16x8*)(Ks + (j * 16 + l16) * 72 + quad * 8);
            bf16x8 bk1 = *(const bf16x8*)(Ks + (j * 16 + l16) * 72 + 32 + quad * 8);
            f32x4 z = (f32x4){0.f, 0.f, 0.f, 0.f};
            z = __builtin_amdgcn_mfma_f32_16x16x32_bf16(bk0, aq0, z, 0, 0, 0);
            s[j] = __builtin_amdgcn_mfma_f32_16x16x32_bf16(bk1, aq1, z, 0, 0, 0);
        }

        // scale (+mask) in log2 domain; per-lane tile max over this lane's 32 keys
        float tm0 = -3.0e38f, tm1 = -3.0e38f, tm2 = -3.0e38f, tm3 = -3.0e38f;
#pragma unroll
        for (int j = 0; j < 8; j++) {
            if (causal) {
                f32x4 m4 = *(const f32x4*)(mask + (long)b * LTOK + k0 + j * 16 + quad * 4);
#pragma unroll
                for (int r = 0; r < 4; r++) {
                    int key = k0 + j * 16 + quad * 4 + r;
                    // additive mask: (1-mk)*NEG*log2e, mk = key<=q ? mask : 0
                    float ad = (key <= qrow) ? fmaf(m4[r], -NEGL2, NEGL2) : NEGL2;
                    s[j][r] = fmaf(s[j][r], C1, ad);
                }
            } else {
#pragma unroll
                for (int r = 0; r < 4; r++) s[j][r] *= C1;
            }
            tm0 = fmaxf(tm0, s[j][0]); tm1 = fmaxf(tm1, s[j][1]);
            tm2 = fmaxf(tm2, s[j][2]); tm3 = fmaxf(tm3, s[j][3]);
        }
        float tmax = fmaxf(fmaxf(tm0, tm1), fmaxf(tm2, tm3));
        // combine across the 4 quads holding the same q-row
        tmax = fmaxf(tmax, __shfl_xor(tmax, 16));
        tmax = fmaxf(tmax, __shfl_xor(tmax, 32));

        float mnew  = fmaxf(m_st, tmax);
        float alpha = __builtin_amdgcn_exp2f(m_st - mnew);
        m_st = mnew;

        // P = exp2(S - m); pack to bf16 pairs in-register
        float rs0 = 0.f, rs1 = 0.f, rs2 = 0.f, rs3 = 0.f;
        unsigned pk[8][2];
#pragma unroll
        for (int j = 0; j < 8; j++) {
            float p0 = __builtin_amdgcn_exp2f(s[j][0] - mnew);
            float p1 = __builtin_amdgcn_exp2f(s[j][1] - mnew);
            float p2 = __builtin_amdgcn_exp2f(s[j][2] - mnew);
            float p3 = __builtin_amdgcn_exp2f(s[j][3] - mnew);
            rs0 += p0; rs1 += p1; rs2 += p2; rs3 += p3;
            asm("v_cvt_pk_bf16_f32 %0, %1, %2" : "=v"(pk[j][0]) : "v"(p0), "v"(p1));
            asm("v_cvt_pk_bf16_f32 %0, %1, %2" : "=v"(pk[j][1]) : "v"(p2), "v"(p3));
        }
        float rsum = (rs0 + rs1) + (rs2 + rs3);
        rsum += __shfl_xor(rsum, 16);
        rsum += __shfl_xor(rsum, 32);
        l_st = l_st * alpha + rsum;

#pragma unroll
        for (int jd = 0; jd < 4; jd++) oacc[jd] *= alpha;

        // O^T += V^T P^T under key-permutation sigma:
        //   B-frag(lane quad,l16)[t] = P[32kk + 16*(t>>2) + 4*quad + (t&3)][l16]
        //   = this lane's own pk registers -> zero shuffles.
        //   A-frag[t] = Vs[jd*16+l16][same sigma] -> two b64 reads.
#pragma unroll
        for (int kk = 0; kk < 4; kk++) {
            unsigned wv[4] = { pk[2 * kk][0], pk[2 * kk][1],
                               pk[2 * kk + 1][0], pk[2 * kk + 1][1] };
            bf16x8 bp; __builtin_memcpy(&bp, wv, 16);
#pragma unroll
            for (int jd = 0; jd < 4; jd++) {
                const u16* vb = Vs + (jd * 16 + l16) * 136 + kk * 32 + quad * 4;
                u16 va[8];
                *(u16x4*)(va)     = *(const u16x4*)(vb);
                *(u16x4*)(va + 4) = *(const u16x4*)(vb + 16);
                bf16x8 av; __builtin_memcpy(&av, va, 16);
                oacc[jd] = __builtin_amdgcn_mfma_f32_16x16x32_bf16(av, bp, oacc[jd], 0, 0, 0);
            }
        }

        if (more) {
            __syncthreads();    // all waves done reading current Ks/Vs
#pragma unroll
            for (int i = 0; i < 4; i++)
                *(u16x8*)(Ks + (i * 32 + krow) * 72 + kcol) = KR[i];
#pragma unroll
            for (int i = 0; i < 4; i++)
                *(u16x8*)(Vs + vrow * 136 + i * 32 + vcol) = VR[i];
            __syncthreads();
        }
    }

    // O^T element (d = jd*16 + quad*4 + r, q = l16): 4 consecutive cols/lane
    float linv = 1.f / l_st;
    long obase = ((long)b * LTOK + qrow) * DDIM + h * 64;
#pragma unroll
    for (int jd = 0; jd < 4; jd++) {
        u16x4 ov;
#pragma unroll
        for (int r = 0; r < 4; r++) ov[r] = f2bf(oacc[jd][r] * linv);
        *(u16x4*)(O + obase + jd * 16 + quad * 4) = ov;
    }
}

// out = LayerNorm(a + b) * g + beta.  a: bf16.  b: bf16 unless b32 (fp32).
// Output: bf16 (o) unless of != nullptr (fp32).  Row length 1024.
__global__ __launch_bounds__(256) void add_ln_kernel(
    const u16* __restrict__ a, const u16* __restrict__ b,
    const float* __restrict__ b32,
    const float* __restrict__ g, const float* __restrict__ bt,
    u16* __restrict__ o, float* __restrict__ of)
{
    long row = blockIdx.x;
    int tid = threadIdx.x;
    __shared__ float red[4];
    const u16* ar = a + row * DDIM;
    float xv[4]; float s = 0.f;
#pragma unroll
    for (int i = 0; i < 4; i++) {
        int c = tid + 256 * i;
        float sum = bf2f(ar[c]) + (b32 ? b32[row * DDIM + c] : bf2f(b[row * DDIM + c]));
        xv[i] = fminf(fmaxf(sum, -1.0e18f), 1.0e18f);
        s += xv[i];
    }
#pragma unroll
    for (int ofs = 32; ofs >= 1; ofs >>= 1) s += __shfl_xor(s, ofs);
    int wave = tid >> 6, lane = tid & 63;
    if (lane == 0) red[wave] = s;
    __syncthreads();
    float mu = (red[0] + red[1] + red[2] + red[3]) * (1.f / 1024.f);
    __syncthreads();
    float v = 0.f;
#pragma unroll
    for (int i = 0; i < 4; i++) { float d = xv[i] - mu; v += d * d; }
#pragma unroll
    for (int ofs = 32; ofs >= 1; ofs >>= 1) v += __shfl_xor(v, ofs);
    if (lane == 0) red[wave] = v;
    __syncthreads();
    float var = (red[0] + red[1] + red[2] + red[3]) * (1.f / 1024.f);
    float inv = rsqrtf(var + 1e-6f);
#pragma unroll
    for (int i = 0; i < 4; i++) {
        int c = tid + 256 * i;
        float r = (xv[i] - mu) * inv * g[c] + bt[c];
        if (of) of[row * DDIM + c] = r;
        else    o [row * DDIM + c] = f2bf(r);
    }
}

// fp32 -> bf16 conversion, 8 elements/thread.
__global__ __launch_bounds__(256) void cvt_kernel(
    const float* __restrict__ src, u16* __restrict__ dst)
{
    long i = ((long)blockIdx.x * 256 + threadIdx.x) * 8;
    u16x8 o;
#pragma unroll
    for (int j = 0; j < 8; j++) o[j] = f2bf(src[i + j]);
    *(u16x8*)(dst + i) = o;
}

// Transpose+cvt the 8 fp32 weight matrices (1024x1024): WT[n][k] = bf16(W[k][n])
__global__ __launch_bounds__(256) void wt_kernel(
    const float* w0, const float* w1, const float* w2, const float* w3,
    const float* w4, const float* w5, const float* w6, const float* w7,
    u16* __restrict__ wt)
{
    const float* srcs[8] = {w0, w1, w2, w3, w4, w5, w6, w7};
    const float* w = srcs[blockIdx.z];
    u16* o = wt + (long)blockIdx.z * DDIM * DDIM;
    __shared__ u16 t[32][33];
    int tx = threadIdx.x & 31, ty = threadIdx.x >> 5;
    int c0 = blockIdx.x << 5, r0 = blockIdx.y << 5;
#pragma unroll
    for (int i = 0; i < 4; i++)
        t[ty + 8 * i][tx] = f2bf(w[(long)(r0 + ty + 8 * i) * DDIM + c0 + tx]);
    __syncthreads();
#pragma unroll
    for (int i = 0; i < 4; i++)
        o[(long)(c0 + ty + 8 * i) * DDIM + r0 + tx] = t[tx][ty + 8 * i];
}

// vt[(b*NH+h)*64 + dd][k] = v[b*LTOK + k][h*64 + dd]   (per-head V transpose)
__global__ __launch_bounds__(256) void vtrans_kernel(
    const u16* __restrict__ v, u16* __restrict__ vt)
{
    int bh = blockIdx.y; int b = bh >> 4, h = bh & 15;
    int k0 = blockIdx.x << 5;
    __shared__ __align__(16) u16 t[32 * 72];
    int kk = threadIdx.x >> 3, c = (threadIdx.x & 7) << 3;
    u16x8 val = *(const u16x8*)(v + ((long)b * LTOK + k0 + kk) * DDIM + h * 64 + c);
    *(u16x8*)(t + kk * 72 + c) = val;
    __syncthreads();
    int dd = threadIdx.x >> 2, k2 = (threadIdx.x & 3) << 3;
    u16x8 o;
#pragma unroll
    for (int j = 0; j < 8; j++) o[j] = t[(k2 + j) * 72 + dd];
    *(u16x8*)(vt + ((long)bh * 64 + dd) * LTOK + k0 + k2) = o;
}

extern "C" void kernel_launch(void* const* d_in, const int* in_sizes, int n_in,
                              void* d_out, int out_size, void* d_ws, size_t ws_size,
                              hipStream_t stream)
{
    const float* x     = (const float*)d_in[0];
    const float* dmsk  = (const float*)d_in[1];
    const float* enc   = (const float*)d_in[2];
    const float* sa_wq = (const float*)d_in[3];  const float* sa_bq = (const float*)d_in[4];
    const float* sa_wk = (const float*)d_in[5];  const float* sa_bk = (const float*)d_in[6];
    const float* sa_wv = (const float*)d_in[7];  const float* sa_bv = (const float*)d_in[8];
    const float* n1_g  = (const float*)d_in[9];  const float* n1_b  = (const float*)d_in[10];
    const float* ca_wq = (const float*)d_in[11]; const float* ca_bq = (const float*)d_in[12];
    const float* ca_wk = (const float*)d_in[13]; const float* ca_bk = (const float*)d_in[14];
    const float* ca_wv = (const float*)d_in[15]; const float* ca_bv = (const float*)d_in[16];
    const float* n2_g  = (const float*)d_in[17]; const float* n2_b  = (const float*)d_in[18];
    const float* int_w = (const float*)d_in[19]; const float* int_b = (const float*)d_in[20];
    const float* out_w = (const float*)d_in[21]; const float* out_b = (const float*)d_in[22];
    const float* out_g = (const float*)d_in[23]; const float* out_bt= (const float*)d_in[24];

    float* outp = (float*)d_out;
    float* visp = outp + (long)NBATCH * LTOK * DDIM;   // attention_vis (fp32)

    // --- workspace: chunk over batches; 7 act buffers / batch + WT ---
    const size_t WTB  = (size_t)8 * DDIM * DDIM * 2;            // 16 MiB
    const size_t BUF1 = (size_t)LTOK * DDIM * 2;                // 1 MiB / batch
    int cb = 16;
    while (cb > 1 && WTB + (size_t)cb * 7 * BUF1 + 8192 > ws_size)
        cb >>= 1;

    char* ws = (char*)d_ws;
    size_t off = 0;
    auto alloc = [&](size_t bytes) -> u16* {
        u16* p = (u16*)(ws + off);
        off += (bytes + 255) & ~(size_t)255;
        return p;
    };
    u16* Bq  = alloc((size_t)cb * BUF1);
    u16* Bk  = alloc((size_t)cb * BUF1);
    u16* Bv  = alloc((size_t)cb * BUF1);
    u16* Bt  = alloc((size_t)cb * BUF1);
    u16* Bt2 = alloc((size_t)cb * BUF1);
    u16* Xb  = alloc((size_t)cb * BUF1);
    u16* Eb  = alloc((size_t)cb * BUF1);
    u16* WT  = alloc(WTB);
    // no memset needed: every region fully written before read.

    u16* Wsaq = WT + 0L * DDIM * DDIM; u16* Wsak = WT + 1L * DDIM * DDIM;
    u16* Wsav = WT + 2L * DDIM * DDIM; u16* Wcaq = WT + 3L * DDIM * DDIM;
    u16* Wcak = WT + 4L * DDIM * DDIM; u16* Wcav = WT + 5L * DDIM * DDIM;
    u16* Wint = WT + 6L * DDIM * DDIM; u16* Wout = WT + 7L * DDIM * DDIM;

    auto gemm = [&](const u16* A, int lda, long sA1, long sA2,
                    const u16* B, int ldb, long sB1, long sB2,
                    u16* C, float* Cf, int ldc, long sC1, long sC2,
                    int M, int N, int K, int Z, int zdiv,
                    const float* bias, float scale, int flags) {
        int tM = (M + 127) / 128, tN = (N + 127) / 128;
        gemm_bt_kernel<<<dim3(tM * tN, Z), dim3(256), 0, stream>>>(
            A, lda, sA1, sA2, B, ldb, sB1, sB2, C, Cf, ldc, sC1, sC2,
            M, N, K, zdiv, bias, scale, flags);
    };

    const long SLD = (long)LTOK * DDIM;       // per-batch row-block stride
    const long SSC = (long)LTOK * LTOK;       // vis elems per batch

    // 0) weight transposes + bf16 cvt (once per call)
    wt_kernel<<<dim3(32, 32, 8), dim3(256), 0, stream>>>(
        sa_wq, sa_wk, sa_wv, ca_wq, ca_wk, ca_wv, int_w, out_w, WT);

    for (int b0 = 0; b0 < NBATCH; b0 += cb) {
        const float* xc = x   + (long)b0 * SLD;
        const float* ec = enc + (long)b0 * SLD;
        const int M = cb * LTOK;
        const int Z = cb * NH;
        const int cvtg = (int)(((long)M * DDIM) / (256 * 8));

        // a) fp32 -> bf16 activation copies
        cvt_kernel<<<dim3(cvtg), dim3(256), 0, stream>>>(xc, Xb);
        cvt_kernel<<<dim3(cvtg), dim3(256), 0, stream>>>(ec, Eb);

        // 1) self-attn q,k,v projections
        gemm(Xb, DDIM, 0, 0, Wsaq, DDIM, 0, 0, Bq, nullptr, DDIM, 0, 0, M, DDIM, DDIM, 1, 1, sa_bq, 1.f, 0);
        gemm(Xb, DDIM, 0, 0, Wsak, DDIM, 0, 0, Bk, nullptr, DDIM, 0, 0, M, DDIM, DDIM, 1, 1, sa_bk, 1.f, 0);
        gemm(Xb, DDIM, 0, 0, Wsav, DDIM, 0, 0, Bv, nullptr, DDIM, 0, 0, M, DDIM, DDIM, 1, 1, sa_bv, 1.f, 0);
        vtrans_kernel<<<dim3(16, Z), dim3(256), 0, stream>>>(Bv, Bt);

        // 2) self-attention (flash, causal+padding), ctx -> Bv
        flash_kernel<<<dim3(Z, 8), dim3(256), 0, stream>>>(
            Bq, Bk, Bt, Bv, dmsk + (long)b0 * LTOK, 1);

        // 3) h = LN(ctx + x_fp32) -> Bq
        add_ln_kernel<<<dim3(M), dim3(256), 0, stream>>>(
            Bv, nullptr, xc, n1_g, n1_b, Bq, nullptr);

        // 4) cross projections: cq->Bk, ck->Bv, cv->Bt
        gemm(Bq, DDIM, 0, 0, Wcaq, DDIM, 0, 0, Bk, nullptr, DDIM, 0, 0, M, DDIM, DDIM, 1, 1, ca_bq, 1.f, 0);
        gemm(Eb, DDIM, 0, 0, Wcak, DDIM, 0, 0, Bv, nullptr, DDIM, 0, 0, M, DDIM, DDIM, 1, 1, ca_bk, 1.f, 0);
        gemm(Eb, DDIM, 0, 0, Wcav, DDIM, 0, 0, Bt, nullptr, DDIM, 0, 0, M, DDIM, DDIM, 1, 1, ca_bv, 1.f, 0);

        // 5) attention_vis = (cq @ ck^T) / 128  -> fp32 d_out
        gemm(Bk, DDIM, SLD, 0, Bv, DDIM, SLD, 0,
             nullptr, visp + (long)b0 * SSC, LTOK, SSC, 0,
             LTOK, LTOK, DDIM, cb, 1, nullptr, 1.f / 128.f, 0);

        // 6) cross-attention (flash, no mask): vt(cv)->Bt2; ctx -> Bt
        vtrans_kernel<<<dim3(16, Z), dim3(256), 0, stream>>>(Bt, Bt2);
        flash_kernel<<<dim3(Z, 8), dim3(256), 0, stream>>>(
            Bk, Bv, Bt2, Bt, nullptr, 0);

        // 7) h2 = LN(h + cactx) -> Bv
        add_ln_kernel<<<dim3(M), dim3(256), 0, stream>>>(
            Bq, Bt, nullptr, n2_g, n2_b, Bv, nullptr);

        // 8) inter = gelu(h2 @ int_w + int_b) -> Bk
        gemm(Bv, DDIM, 0, 0, Wint, DDIM, 0, 0, Bk, nullptr, DDIM, 0, 0, M, DDIM, DDIM, 1, 1, int_b, 1.f, 1);
        // 9) G = inter @ out_w + out_b -> Bt
        gemm(Bk, DDIM, 0, 0, Wout, DDIM, 0, 0, Bt, nullptr, DDIM, 0, 0, M, DDIM, DDIM, 1, 1, out_b, 1.f, 0);
        // 10) out = LN(G + inter) -> fp32 d_out
        add_ln_kernel<<<dim3(M), dim3(256), 0, stream>>>(
            Bt, Bk, nullptr, out_g, out_bt, nullptr, outp + (long)b0 * SLD);
    }
}

// Round 3
// 599.215 us; speedup vs baseline: 1.1158x; 1.0283x over previous
//
#include <hip/hip_runtime.h>
#include <hip/hip_bf16.h>
#include <math.h>

// Problem constants
#define DDIM 1024
#define NH   16
#define LTOK 512
#define NBATCH 16

typedef unsigned short u16;
typedef unsigned short u16x8 __attribute__((ext_vector_type(8)));
typedef unsigned short u16x4 __attribute__((ext_vector_type(4)));
typedef __bf16 bf16x8 __attribute__((ext_vector_type(8)));
typedef float f32x4 __attribute__((ext_vector_type(4)));

typedef __attribute__((address_space(1))) void as1_void;
typedef __attribute__((address_space(3))) void as3_void;

__device__ __forceinline__ void llds16(const u16* g, u16* l) {
    // async 16B global->LDS DMA; LDS dest = wave-uniform base + lane*16B
    __builtin_amdgcn_global_load_lds((as1_void*)g, (as3_void*)l, 16, 0, 0);
}

__device__ __forceinline__ float bf2f(u16 u) {
    unsigned v = ((unsigned)u) << 16;
    float f; __builtin_memcpy(&f, &v, 4); return f;
}
__device__ __forceinline__ u16 f2bf(float f) {
    unsigned u; __builtin_memcpy(&u, &f, 4);
    u += 0x7fffu + ((u >> 16) & 1u);   // RNE
    return (u16)(u >> 16);
}

// ---------------------------------------------------------------------------
// Generic MFMA GEMM (projections / vis):  C = act(scale*(A@BT^T)+bias)
// 128x128 tile, BK=32, global_load_lds staging (m97 shape). K>=512 users only.
// XCD swizzle (T1): when tilesM%8==0, group all tilesN blocks of one A-panel
// onto one XCD (dispatch round-robins linear wg id across the 8 XCDs).
// Fused-N launches (QKV: N=3072, cross-KV: N=2048) raise grid to 4-6
// blocks/CU so implicit wave overlap hides the barrier drain.
// ---------------------------------------------------------------------------
__global__ __launch_bounds__(256) void gemm_bt_kernel(
    const u16* __restrict__ A, int lda, long sA1, long sA2,
    const u16* __restrict__ B, int ldb, long sB1, long sB2,
    u16* __restrict__ C, float* __restrict__ Cf, int ldc, long sC1, long sC2,
    int M, int N, int K, int zdiv,
    const float* __restrict__ bias, float scale, int flags)
{
    __shared__ __align__(16) u16 As[128 * 32];
    __shared__ __align__(16) u16 Bs[128 * 32];

    const int z  = blockIdx.y;
    const int zb = z / zdiv, zh = z - zb * zdiv;
    const u16* Ab = A + (long)zb * sA1 + (long)zh * sA2;
    const u16* Bb = B + (long)zb * sB1 + (long)zh * sB2;
    u16*   Cb  = C  ? C  + (long)zb * sC1 + (long)zh * sC2 : nullptr;
    float* Cfb = Cf ? Cf + (long)zb * sC1 + (long)zh * sC2 : nullptr;

    const int tilesN = (N + 127) >> 7;
    const int tilesM = (M + 127) >> 7;
    int tm, tn;
    if ((tilesM & 7) == 0) {
        // bijective XCD-grouping swizzle: tm % 8 == linear-wg % 8
        const int xcd = blockIdx.x & 7, idx = blockIdx.x >> 3;
        const int mg  = tilesM >> 3;
        tm = ((idx % mg) << 3) | xcd;
        tn = idx / mg;
    } else {
        tm = blockIdx.x / tilesN;
        tn = blockIdx.x - tm * tilesN;
    }
    const int m0 = tm << 7, n0 = tn << 7;

    const int tid  = threadIdx.x;
    const int lane = tid & 63;
    const int wave = tid >> 6;
    const int wm = (wave & 1) << 6, wn = (wave >> 1) << 6;
    const int quad = lane >> 4, l16 = lane & 15;

    f32x4 acc[4][4];
#pragma unroll
    for (int i = 0; i < 4; i++)
#pragma unroll
        for (int j = 0; j < 4; j++) acc[i][j] = (f32x4){0.f, 0.f, 0.f, 0.f};

    const int lrA = (wave << 5) + (lane >> 2);
    const int lc  = (lane & 3) << 3;
    int ra0 = m0 + lrA;      if (ra0 > M - 1) ra0 = M - 1;
    int ra1 = m0 + lrA + 16; if (ra1 > M - 1) ra1 = M - 1;
    int rb0 = n0 + lrA;      if (rb0 > N - 1) rb0 = N - 1;
    int rb1 = n0 + lrA + 16; if (rb1 > N - 1) rb1 = N - 1;
    const u16* gA0 = Ab + (long)ra0 * lda + lc;
    const u16* gA1 = Ab + (long)ra1 * lda + lc;
    const u16* gB0 = Bb + (long)rb0 * ldb + lc;
    const u16* gB1 = Bb + (long)rb1 * ldb + lc;
    u16* lA0 = As + ((wave << 5) +  0) * 32;
    u16* lA1 = As + ((wave << 5) + 16) * 32;
    u16* lB0 = Bs + ((wave << 5) +  0) * 32;
    u16* lB1 = Bs + ((wave << 5) + 16) * 32;

    for (int k0 = 0; k0 < K; k0 += 32) {
        __syncthreads();
        llds16(gA0 + k0, lA0);
        llds16(gA1 + k0, lA1);
        llds16(gB0 + k0, lB0);
        llds16(gB1 + k0, lB1);
        __syncthreads();

        bf16x8 af[4], bfr[4];
#pragma unroll
        for (int t = 0; t < 4; t++)
            af[t] = *(const bf16x8*)(As + (wm + t * 16 + l16) * 32 + quad * 8);
#pragma unroll
        for (int t = 0; t < 4; t++)
            bfr[t] = *(const bf16x8*)(Bs + (wn + t * 16 + l16) * 32 + quad * 8);
#pragma unroll
        for (int i = 0; i < 4; i++)
#pragma unroll
            for (int j = 0; j < 4; j++)
                acc[i][j] = __builtin_amdgcn_mfma_f32_16x16x32_bf16(
                    af[i], bfr[j], acc[i][j], 0, 0, 0);
    }

#pragma unroll
    for (int j = 0; j < 4; j++) {
        int col  = n0 + wn + j * 16 + l16;
        int colc = col < N ? col : N - 1;
        float bv = bias ? bias[colc] : 0.f;
#pragma unroll
        for (int i = 0; i < 4; i++) {
#pragma unroll
            for (int r = 0; r < 4; r++) {
                int row = m0 + wm + i * 16 + quad * 4 + r;
                float v = acc[i][j][r] * scale + bv;
                if (flags & 1)
                    v = 0.5f * v * (1.f + erff(v * 0.70710678118654752f));
                if (row < M && col < N) {
                    if (Cfb) Cfb[(long)row * ldc + col] = v;
                    else     Cb [(long)row * ldc + col] = f2bf(v);
                }
            }
        }
    }
}

// ---------------------------------------------------------------------------
// Flash attention: O = softmax(scale*Q K^T + mask) V, head dim 64, L = 512.
//   Q: (b, 512, ldq) bf16, head h at cols h*64;  K: (b, 512, ldk) bf16
//   VT: (bh, 64, 512) bf16 (per-head V^T);  O: (b, 512, 1024) bf16
// grid (bh=cb*16, qt=8): bh FAST so the 8 qt-blocks of one head land on the
// SAME XCD (256 % 8 == 0) -> K/VT fetched once per XCD, L2-served after.
// Block: 4 waves, 64 q-rows; K-tile(128x64) + VT-tile(64x128) staged in LDS.
//
// Swapped-operand S^T = mfma(K,Q): each lane's 32 S values belong to ONE
// q-row (q = l16); softmax fully in-register (exp2 domain, v_cvt_pk_bf16).
// ZERO-SHUFFLE PV: key axis permuted by sigma(kk,quad,t) =
// 32kk + 16*(t>>2) + 4*quad + (t&3) so the B-fragment is the lane's own pk
// registers; V's A-fragment reads the same sigma as two b64 LDS loads.
// T14 async-STAGE: next tile's K/V global loads issue before compute.
// ---------------------------------------------------------------------------
__global__ __launch_bounds__(256, 4) void flash_kernel(
    const u16* __restrict__ Q, const u16* __restrict__ K,
    const u16* __restrict__ VT, u16* __restrict__ O,
    const float* __restrict__ mask, int causal, int ldq, int ldk)
{
    __shared__ __align__(16) u16 Ks[128 * 72];    // keys x dims, pad 64->72
    __shared__ __align__(16) u16 Vs[64 * 136];    // dims x keys, pad 128->136
    const int tid  = threadIdx.x;
    const int wave = tid >> 6, lane = tid & 63;
    const int quad = lane >> 4, l16 = lane & 15;
    const int bh = blockIdx.x, qt = blockIdx.y, b = bh >> 4, h = bh & 15;
    const int qbase = qt * 64 + wave * 16;
    const int qrow  = qbase + l16;            // this lane's q row

    // Q fragment (held all kernel).  Used as the MFMA *B* operand:
    // B[k=quad*8+t][n=l16] = Q[qbase+l16][d=quad*8+t]
    const u16* qp = Q + ((long)b * LTOK + qrow) * ldq + h * 64 + quad * 8;
    bf16x8 aq0 = *(const bf16x8*)(qp);
    bf16x8 aq1 = *(const bf16x8*)(qp + 32);

    f32x4 oacc[4];
#pragma unroll
    for (int jd = 0; jd < 4; jd++) oacc[jd] = (f32x4){0.f, 0.f, 0.f, 0.f};
    float m_st = -3.0e38f;      // running max, log2 domain
    float l_st = 0.f;           // running denom

    // staging maps
    const int krow = tid >> 3,       kcol = (tid & 7) << 3;   // K: 32 rows/issue
    const int vrow = tid >> 2,       vcol = (tid & 3) << 3;   // VT: 64 rows, 4x8 cols/issue
    const u16* gK = K + ((long)b * LTOK + krow) * ldk + h * 64 + kcol;
    const u16* gV = VT + ((long)bh * 64 + vrow) * LTOK + vcol;

    const float C1    = 0.125f * 1.44269504088896340736f;   // scale*log2(e)
    const float NEGL2 = -10000.0f * 1.44269504088896340736f;

    const int nkt = causal ? ((qt * 64 + 63) >> 7) + 1 : (LTOK >> 7);

    // ---- prologue: stage tile 0 ----
    u16x8 KR[4], VR[4];
#pragma unroll
    for (int i = 0; i < 4; i++) KR[i] = *(const u16x8*)(gK + (long)(i * 32) * ldk);
#pragma unroll
    for (int i = 0; i < 4; i++) VR[i] = *(const u16x8*)(gV + i * 32);
#pragma unroll
    for (int i = 0; i < 4; i++)
        *(u16x8*)(Ks + (i * 32 + krow) * 72 + kcol) = KR[i];
#pragma unroll
    for (int i = 0; i < 4; i++)
        *(u16x8*)(Vs + vrow * 136 + i * 32 + vcol) = VR[i];
    __syncthreads();

    for (int kt = 0; kt < nkt; kt++) {
        const int k0 = kt << 7;
        const bool more = (kt + 1 < nkt);     // block-uniform

        // T14: issue next tile's global loads now; write to LDS after compute
        if (more) {
            const int kn = k0 + 128;
#pragma unroll
            for (int i = 0; i < 4; i++)
                KR[i] = *(const u16x8*)(gK + (long)(kn + i * 32) * ldk);
#pragma unroll
            for (int i = 0; i < 4; i++)
                VR[i] = *(const u16x8*)(gV + kn + i * 32);
        }

        // S^T = K Q^T : C-layout col = l16 = q, row = key = j*16 + quad*4 + r
        f32x4 s[8];
#pragma unroll
        for (int j = 0; j < 8; j++) {
            bf16x8 bk0 = *(const bf16x8*)(Ks + (j * 16 + l16) * 72 + quad * 8);
            bf16x8 bk1 = *(const bf16x8*)(Ks + (j * 16 + l16) * 72 + 32 + quad * 8);
            f32x4 z = (f32x4){0.f, 0.f, 0.f, 0.f};
            z = __builtin_amdgcn_mfma_f32_16x16x32_bf16(bk0, aq0, z, 0, 0, 0);
            s[j] = __builtin_amdgcn_mfma_f32_16x16x32_bf16(bk1, aq1, z, 0, 0, 0);
        }

        // scale (+mask) in log2 domain; per-lane tile max over this lane's 32 keys
        float tm0 = -3.0e38f, tm1 = -3.0e38f, tm2 = -3.0e38f, tm3 = -3.0e38f;
#pragma unroll
        for (int j = 0; j < 8; j++) {
            if (causal) {
                f32x4 m4 = *(const f32x4*)(mask + (long)b * LTOK + k0 + j * 16 + quad * 4);
#pragma unroll
                for (int r = 0; r < 4; r++) {
                    int key = k0 + j * 16 + quad * 4 + r;
                    // additive mask: (1-mk)*NEG*log2e, mk = key<=q ? mask : 0
                    float ad = (key <= qrow) ? fmaf(m4[r], -NEGL2, NEGL2) : NEGL2;
                    s[j][r] = fmaf(s[j][r], C1, ad);
                }
            } else {
#pragma unroll
                for (int r = 0; r < 4; r++) s[j][r] *= C1;
            }
            tm0 = fmaxf(tm0, s[j][0]); tm1 = fmaxf(tm1, s[j][1]);
            tm2 = fmaxf(tm2, s[j][2]); tm3 = fmaxf(tm3, s[j][3]);
        }
        float tmax = fmaxf(fmaxf(tm0, tm1), fmaxf(tm2, tm3));
        // combine across the 4 quads holding the same q-row
        tmax = fmaxf(tmax, __shfl_xor(tmax, 16));
        tmax = fmaxf(tmax, __shfl_xor(tmax, 32));

        float mnew  = fmaxf(m_st, tmax);
        float alpha = __builtin_amdgcn_exp2f(m_st - mnew);
        m_st = mnew;

        // P = exp2(S - m); pack to bf16 pairs in-register
        float rs0 = 0.f, rs1 = 0.f, rs2 = 0.f, rs3 = 0.f;
        unsigned pk[8][2];
#pragma unroll
        for (int j = 0; j < 8; j++) {
            float p0 = __builtin_amdgcn_exp2f(s[j][0] - mnew);
            float p1 = __builtin_amdgcn_exp2f(s[j][1] - mnew);
            float p2 = __builtin_amdgcn_exp2f(s[j][2] - mnew);
            float p3 = __builtin_amdgcn_exp2f(s[j][3] - mnew);
            rs0 += p0; rs1 += p1; rs2 += p2; rs3 += p3;
            asm("v_cvt_pk_bf16_f32 %0, %1, %2" : "=v"(pk[j][0]) : "v"(p0), "v"(p1));
            asm("v_cvt_pk_bf16_f32 %0, %1, %2" : "=v"(pk[j][1]) : "v"(p2), "v"(p3));
        }
        float rsum = (rs0 + rs1) + (rs2 + rs3);
        rsum += __shfl_xor(rsum, 16);
        rsum += __shfl_xor(rsum, 32);
        l_st = l_st * alpha + rsum;

#pragma unroll
        for (int jd = 0; jd < 4; jd++) oacc[jd] *= alpha;

        // O^T += V^T P^T under key-permutation sigma:
        //   B-frag(lane quad,l16)[t] = P[32kk + 16*(t>>2) + 4*quad + (t&3)][l16]
        //   = this lane's own pk registers -> zero shuffles.
        //   A-frag[t] = Vs[jd*16+l16][same sigma] -> two b64 reads.
#pragma unroll
        for (int kk = 0; kk < 4; kk++) {
            unsigned wv[4] = { pk[2 * kk][0], pk[2 * kk][1],
                               pk[2 * kk + 1][0], pk[2 * kk + 1][1] };
            bf16x8 bp; __builtin_memcpy(&bp, wv, 16);
#pragma unroll
            for (int jd = 0; jd < 4; jd++) {
                const u16* vb = Vs + (jd * 16 + l16) * 136 + kk * 32 + quad * 4;
                u16 va[8];
                *(u16x4*)(va)     = *(const u16x4*)(vb);
                *(u16x4*)(va + 4) = *(const u16x4*)(vb + 16);
                bf16x8 av; __builtin_memcpy(&av, va, 16);
                oacc[jd] = __builtin_amdgcn_mfma_f32_16x16x32_bf16(av, bp, oacc[jd], 0, 0, 0);
            }
        }

        if (more) {
            __syncthreads();    // all waves done reading current Ks/Vs
#pragma unroll
            for (int i = 0; i < 4; i++)
                *(u16x8*)(Ks + (i * 32 + krow) * 72 + kcol) = KR[i];
#pragma unroll
            for (int i = 0; i < 4; i++)
                *(u16x8*)(Vs + vrow * 136 + i * 32 + vcol) = VR[i];
            __syncthreads();
        }
    }

    // O^T element (d = jd*16 + quad*4 + r, q = l16): 4 consecutive cols/lane
    float linv = 1.f / l_st;
    long obase = ((long)b * LTOK + qrow) * DDIM + h * 64;
#pragma unroll
    for (int jd = 0; jd < 4; jd++) {
        u16x4 ov;
#pragma unroll
        for (int r = 0; r < 4; r++) ov[r] = f2bf(oacc[jd][r] * linv);
        *(u16x4*)(O + obase + jd * 16 + quad * 4) = ov;
    }
}

// out = LayerNorm(a + b) * g + beta.  a: bf16.  b: bf16 unless b32 (fp32).
// Output: bf16 (o) unless of != nullptr (fp32).  Row length 1024.
__global__ __launch_bounds__(256) void add_ln_kernel(
    const u16* __restrict__ a, const u16* __restrict__ b,
    const float* __restrict__ b32,
    const float* __restrict__ g, const float* __restrict__ bt,
    u16* __restrict__ o, float* __restrict__ of)
{
    long row = blockIdx.x;
    int tid = threadIdx.x;
    __shared__ float red[4];
    const u16* ar = a + row * DDIM;
    float xv[4]; float s = 0.f;
#pragma unroll
    for (int i = 0; i < 4; i++) {
        int c = tid + 256 * i;
        float sum = bf2f(ar[c]) + (b32 ? b32[row * DDIM + c] : bf2f(b[row * DDIM + c]));
        xv[i] = fminf(fmaxf(sum, -1.0e18f), 1.0e18f);
        s += xv[i];
    }
#pragma unroll
    for (int ofs = 32; ofs >= 1; ofs >>= 1) s += __shfl_xor(s, ofs);
    int wave = tid >> 6, lane = tid & 63;
    if (lane == 0) red[wave] = s;
    __syncthreads();
    float mu = (red[0] + red[1] + red[2] + red[3]) * (1.f / 1024.f);
    __syncthreads();
    float v = 0.f;
#pragma unroll
    for (int i = 0; i < 4; i++) { float d = xv[i] - mu; v += d * d; }
#pragma unroll
    for (int ofs = 32; ofs >= 1; ofs >>= 1) v += __shfl_xor(v, ofs);
    if (lane == 0) red[wave] = v;
    __syncthreads();
    float var = (red[0] + red[1] + red[2] + red[3]) * (1.f / 1024.f);
    float inv = rsqrtf(var + 1e-6f);
#pragma unroll
    for (int i = 0; i < 4; i++) {
        int c = tid + 256 * i;
        float r = (xv[i] - mu) * inv * g[c] + bt[c];
        if (of) of[row * DDIM + c] = r;
        else    o [row * DDIM + c] = f2bf(r);
    }
}

// fp32 -> bf16 conversion, 8 elements/thread.
__global__ __launch_bounds__(256) void cvt_kernel(
    const float* __restrict__ src, u16* __restrict__ dst)
{
    long i = ((long)blockIdx.x * 256 + threadIdx.x) * 8;
    u16x8 o;
#pragma unroll
    for (int j = 0; j < 8; j++) o[j] = f2bf(src[i + j]);
    *(u16x8*)(dst + i) = o;
}

// Transpose+cvt the 8 fp32 weight matrices (1024x1024): WT[n][k] = bf16(W[k][n])
__global__ __launch_bounds__(256) void wt_kernel(
    const float* w0, const float* w1, const float* w2, const float* w3,
    const float* w4, const float* w5, const float* w6, const float* w7,
    u16* __restrict__ wt)
{
    const float* srcs[8] = {w0, w1, w2, w3, w4, w5, w6, w7};
    const float* w = srcs[blockIdx.z];
    u16* o = wt + (long)blockIdx.z * DDIM * DDIM;
    __shared__ u16 t[32][33];
    int tx = threadIdx.x & 31, ty = threadIdx.x >> 5;
    int c0 = blockIdx.x << 5, r0 = blockIdx.y << 5;
#pragma unroll
    for (int i = 0; i < 4; i++)
        t[ty + 8 * i][tx] = f2bf(w[(long)(r0 + ty + 8 * i) * DDIM + c0 + tx]);
    __syncthreads();
#pragma unroll
    for (int i = 0; i < 4; i++)
        o[(long)(c0 + ty + 8 * i) * DDIM + r0 + tx] = t[tx][ty + 8 * i];
}

// Concatenate up to 3 bias vectors (1024 each) into one fp32 array.
__global__ __launch_bounds__(256) void biascat_kernel(
    const float* __restrict__ b0, const float* __restrict__ b1,
    const float* __restrict__ b2, float* __restrict__ dst)
{
    int i = blockIdx.x * 256 + threadIdx.x;
    const float* s = (i < 1024) ? b0 : (i < 2048) ? b1 : b2;
    dst[i] = s[i & 1023];
}

// vt[(b*NH+h)*64 + dd][k] = v[b*LTOK + k][h*64 + dd]   (per-head V transpose)
__global__ __launch_bounds__(256) void vtrans_kernel(
    const u16* __restrict__ v, u16* __restrict__ vt, int ldv)
{
    int bh = blockIdx.y; int b = bh >> 4, h = bh & 15;
    int k0 = blockIdx.x << 5;
    __shared__ __align__(16) u16 t[32 * 72];
    int kk = threadIdx.x >> 3, c = (threadIdx.x & 7) << 3;
    u16x8 val = *(const u16x8*)(v + ((long)b * LTOK + k0 + kk) * ldv + h * 64 + c);
    *(u16x8*)(t + kk * 72 + c) = val;
    __syncthreads();
    int dd = threadIdx.x >> 2, k2 = (threadIdx.x & 3) << 3;
    u16x8 o;
#pragma unroll
    for (int j = 0; j < 8; j++) o[j] = t[(k2 + j) * 72 + dd];
    *(u16x8*)(vt + ((long)bh * 64 + dd) * LTOK + k0 + k2) = o;
}

extern "C" void kernel_launch(void* const* d_in, const int* in_sizes, int n_in,
                              void* d_out, int out_size, void* d_ws, size_t ws_size,
                              hipStream_t stream)
{
    const float* x     = (const float*)d_in[0];
    const float* dmsk  = (const float*)d_in[1];
    const float* enc   = (const float*)d_in[2];
    const float* sa_wq = (const float*)d_in[3];  const float* sa_bq = (const float*)d_in[4];
    const float* sa_wk = (const float*)d_in[5];  const float* sa_bk = (const float*)d_in[6];
    const float* sa_wv = (const float*)d_in[7];  const float* sa_bv = (const float*)d_in[8];
    const float* n1_g  = (const float*)d_in[9];  const float* n1_b  = (const float*)d_in[10];
    const float* ca_wq = (const float*)d_in[11]; const float* ca_bq = (const float*)d_in[12];
    const float* ca_wk = (const float*)d_in[13]; const float* ca_bk = (const float*)d_in[14];
    const float* ca_wv = (const float*)d_in[15]; const float* ca_bv = (const float*)d_in[16];
    const float* n2_g  = (const float*)d_in[17]; const float* n2_b  = (const float*)d_in[18];
    const float* int_w = (const float*)d_in[19]; const float* int_b = (const float*)d_in[20];
    const float* out_w = (const float*)d_in[21]; const float* out_b = (const float*)d_in[22];
    const float* out_g = (const float*)d_in[23]; const float* out_bt= (const float*)d_in[24];

    float* outp = (float*)d_out;
    float* visp = outp + (long)NBATCH * LTOK * DDIM;   // attention_vis (fp32)

    // --- workspace: chunk over batches; 7 buffer units / batch + WT + bias ---
    const size_t WTB  = (size_t)8 * DDIM * DDIM * 2;            // 16 MiB
    const size_t BUF1 = (size_t)LTOK * DDIM * 2;                // 1 MiB / batch
    int cb = 16;
    while (cb > 1 && WTB + (size_t)cb * 7 * BUF1 + 32768 > ws_size)
        cb >>= 1;

    char* ws = (char*)d_ws;
    size_t off = 0;
    auto alloc = [&](size_t bytes) -> u16* {
        u16* p = (u16*)(ws + off);
        off += (bytes + 255) & ~(size_t)255;
        return p;
    };
    u16* Xb  = alloc((size_t)cb * BUF1);          // Xb -> h
    u16* Eb  = alloc((size_t)cb * BUF1);          // Eb -> h2
    u16* Q3  = alloc((size_t)cb * 3 * BUF1);      // qkv(ld 3072) -> CQ | CKV -> I | G
    u16* Vt  = alloc((size_t)cb * BUF1);          // per-head V^T (self, then cross)
    u16* Cx  = alloc((size_t)cb * BUF1);          // attn ctx (self, then cross)
    u16* WT  = alloc(WTB);
    float* biasQKV = (float*)alloc(3072 * sizeof(float));
    float* biasKV  = (float*)alloc(2048 * sizeof(float));
    // no memset needed: every region fully written before read.

    u16* Wsaq = WT + 0L * DDIM * DDIM;   // [Wsaq|Wsak|Wsav] contiguous => fused B
    u16* Wcaq = WT + 3L * DDIM * DDIM;
    u16* Wcak = WT + 4L * DDIM * DDIM;   // [Wcak|Wcav] contiguous => fused B
    u16* Wint = WT + 6L * DDIM * DDIM;
    u16* Wout = WT + 7L * DDIM * DDIM;

    auto gemm = [&](const u16* A, int lda, long sA1, long sA2,
                    const u16* B, int ldb, long sB1, long sB2,
                    u16* C, float* Cf, int ldc, long sC1, long sC2,
                    int M, int N, int K, int Z, int zdiv,
                    const float* bias, float scale, int flags) {
        int tM = (M + 127) / 128, tN = (N + 127) / 128;
        gemm_bt_kernel<<<dim3(tM * tN, Z), dim3(256), 0, stream>>>(
            A, lda, sA1, sA2, B, ldb, sB1, sB2, C, Cf, ldc, sC1, sC2,
            M, N, K, zdiv, bias, scale, flags);
    };

    const long SLD = (long)LTOK * DDIM;       // per-batch row-block stride
    const long SSC = (long)LTOK * LTOK;       // vis elems per batch

    // 0) weight transposes + bf16 cvt + bias packs (once per call)
    wt_kernel<<<dim3(32, 32, 8), dim3(256), 0, stream>>>(
        sa_wq, sa_wk, sa_wv, ca_wq, ca_wk, ca_wv, int_w, out_w, WT);
    biascat_kernel<<<dim3(12), dim3(256), 0, stream>>>(sa_bq, sa_bk, sa_bv, biasQKV);
    biascat_kernel<<<dim3(8),  dim3(256), 0, stream>>>(ca_bk, ca_bv, ca_bv, biasKV);

    for (int b0 = 0; b0 < NBATCH; b0 += cb) {
        const float* xc = x   + (long)b0 * SLD;
        const float* ec = enc + (long)b0 * SLD;
        const int M = cb * LTOK;
        const int Z = cb * NH;
        const int cvtg = (int)(((long)M * DDIM) / (256 * 8));

        u16* h   = Xb;                                   // after QKV proj
        u16* CQ  = Q3;                                   // after self-attn
        u16* CKV = Q3 + (size_t)cb * LTOK * DDIM;        // cross k|v, ld 2048
        u16* I   = Q3;                                   // after cross-attn
        u16* G   = Q3 + (size_t)cb * LTOK * DDIM;
        u16* h2  = Eb;                                   // after cross proj

        // a) fp32 -> bf16 activation copies
        cvt_kernel<<<dim3(cvtg), dim3(256), 0, stream>>>(xc, Xb);
        cvt_kernel<<<dim3(cvtg), dim3(256), 0, stream>>>(ec, Eb);

        // 1) fused self-attn q|k|v projection: N=3072, ld 3072 (1536 blocks)
        gemm(Xb, DDIM, 0, 0, Wsaq, DDIM, 0, 0, Q3, nullptr, 3 * DDIM, 0, 0,
             M, 3 * DDIM, DDIM, 1, 1, biasQKV, 1.f, 0);
        vtrans_kernel<<<dim3(16, Z), dim3(256), 0, stream>>>(Q3 + 2 * DDIM, Vt, 3 * DDIM);

        // 2) self-attention (flash, causal+padding), ctx -> Cx
        flash_kernel<<<dim3(Z, 8), dim3(256), 0, stream>>>(
            Q3, Q3 + DDIM, Vt, Cx, dmsk + (long)b0 * LTOK, 1, 3 * DDIM, 3 * DDIM);

        // 3) h = LN(ctx + x_fp32) -> h (Xb reuse)
        add_ln_kernel<<<dim3(M), dim3(256), 0, stream>>>(
            Cx, nullptr, xc, n1_g, n1_b, h, nullptr);

        // 4) cq -> CQ;  fused cross k|v -> CKV (N=2048, ld 2048, 1024 blocks)
        gemm(h, DDIM, 0, 0, Wcaq, DDIM, 0, 0, CQ, nullptr, DDIM, 0, 0,
             M, DDIM, DDIM, 1, 1, ca_bq, 1.f, 0);
        gemm(Eb, DDIM, 0, 0, Wcak, DDIM, 0, 0, CKV, nullptr, 2 * DDIM, 0, 0,
             M, 2 * DDIM, DDIM, 1, 1, biasKV, 1.f, 0);

        // 5) attention_vis = (cq @ ck^T) / 128  -> fp32 d_out
        gemm(CQ, DDIM, SLD, 0, CKV, 2 * DDIM, (long)LTOK * 2 * DDIM, 0,
             nullptr, visp + (long)b0 * SSC, LTOK, SSC, 0,
             LTOK, LTOK, DDIM, cb, 1, nullptr, 1.f / 128.f, 0);

        // 6) cross-attention (flash, no mask): vt(cv)->Vt; ctx -> Cx
        vtrans_kernel<<<dim3(16, Z), dim3(256), 0, stream>>>(CKV + DDIM, Vt, 2 * DDIM);
        flash_kernel<<<dim3(Z, 8), dim3(256), 0, stream>>>(
            CQ, CKV, Vt, Cx, nullptr, 0, DDIM, 2 * DDIM);

        // 7) h2 = LN(h + cactx) -> h2 (Eb reuse)
        add_ln_kernel<<<dim3(M), dim3(256), 0, stream>>>(
            h, Cx, nullptr, n2_g, n2_b, h2, nullptr);

        // 8) inter = gelu(h2 @ int_w + int_b) -> I
        gemm(h2, DDIM, 0, 0, Wint, DDIM, 0, 0, I, nullptr, DDIM, 0, 0,
             M, DDIM, DDIM, 1, 1, int_b, 1.f, 1);
        // 9) G = inter @ out_w + out_b -> G
        gemm(I, DDIM, 0, 0, Wout, DDIM, 0, 0, G, nullptr, DDIM, 0, 0,
             M, DDIM, DDIM, 1, 1, out_b, 1.f, 0);
        // 10) out = LN(G + inter) -> fp32 d_out
        add_ln_kernel<<<dim3(M), dim3(256), 0, stream>>>(
            G, I, nullptr, out_g, out_bt, nullptr, outp + (long)b0 * SLD);
    }
}

// Round 4
// 577.885 us; speedup vs baseline: 1.1570x; 1.0369x over previous
//
#include <hip/hip_runtime.h>
#include <hip/hip_bf16.h>
#include <math.h>

// Problem constants
#define DDIM 1024
#define NH   16
#define LTOK 512
#define NBATCH 16

typedef unsigned short u16;
typedef unsigned short u16x8 __attribute__((ext_vector_type(8)));
typedef unsigned short u16x4 __attribute__((ext_vector_type(4)));
typedef __bf16 bf16x8 __attribute__((ext_vector_type(8)));
typedef float f32x4 __attribute__((ext_vector_type(4)));

typedef __attribute__((address_space(1))) void as1_void;
typedef __attribute__((address_space(3))) void as3_void;

__device__ __forceinline__ void llds16(const u16* g, u16* l) {
    // async 16B global->LDS DMA; LDS dest = wave-uniform base + lane*16B
    __builtin_amdgcn_global_load_lds((as1_void*)g, (as3_void*)l, 16, 0, 0);
}

__device__ __forceinline__ float bf2f(u16 u) {
    unsigned v = ((unsigned)u) << 16;
    float f; __builtin_memcpy(&f, &v, 4); return f;
}
__device__ __forceinline__ u16 f2bf(float f) {
    unsigned u; __builtin_memcpy(&u, &f, 4);
    u += 0x7fffu + ((u >> 16) & 1u);   // RNE
    return (u16)(u >> 16);
}

// ---------------------------------------------------------------------------
// Generic MFMA GEMM (projections / vis):  C = act(scale*(A@BT^T)+bias)
// 128x128 tile, BK=32, global_load_lds staging. K>=512 users only.
// T3 2-phase double-buffer: per K-step, STAGE next tile into buf^1 (async
// DMA in flight across the whole compute phase), ds_read+MFMA current buf,
// ONE barrier (compiler's pre-s_barrier vmcnt(0)+lgkmcnt(0) drain makes the
// swap safe).  vs 1-phase m97 loop: staging latency fully hidden, half the
// barriers -- critical at K=1024 (32 steps).
// XCD swizzle (T1) when tilesM%8==0.  Fused-N launches (QKV N=3072,
// cross-KV N=2048) keep grid at 4-6 blocks/CU.
// ---------------------------------------------------------------------------
__global__ __launch_bounds__(256) void gemm_bt_kernel(
    const u16* __restrict__ A, int lda, long sA1, long sA2,
    const u16* __restrict__ B, int ldb, long sB1, long sB2,
    u16* __restrict__ C, float* __restrict__ Cf, int ldc, long sC1, long sC2,
    int M, int N, int K, int zdiv,
    const float* __restrict__ bias, float scale, int flags)
{
    __shared__ __align__(16) u16 As[2 * 128 * 32];   // double-buffered
    __shared__ __align__(16) u16 Bs[2 * 128 * 32];
    const int BUF = 128 * 32;

    const int z  = blockIdx.y;
    const int zb = z / zdiv, zh = z - zb * zdiv;
    const u16* Ab = A + (long)zb * sA1 + (long)zh * sA2;
    const u16* Bb = B + (long)zb * sB1 + (long)zh * sB2;
    u16*   Cb  = C  ? C  + (long)zb * sC1 + (long)zh * sC2 : nullptr;
    float* Cfb = Cf ? Cf + (long)zb * sC1 + (long)zh * sC2 : nullptr;

    const int tilesN = (N + 127) >> 7;
    const int tilesM = (M + 127) >> 7;
    int tm, tn;
    if ((tilesM & 7) == 0) {
        // bijective XCD-grouping swizzle: tm % 8 == linear-wg % 8
        const int xcd = blockIdx.x & 7, idx = blockIdx.x >> 3;
        const int mg  = tilesM >> 3;
        tm = ((idx % mg) << 3) | xcd;
        tn = idx / mg;
    } else {
        tm = blockIdx.x / tilesN;
        tn = blockIdx.x - tm * tilesN;
    }
    const int m0 = tm << 7, n0 = tn << 7;

    const int tid  = threadIdx.x;
    const int lane = tid & 63;
    const int wave = tid >> 6;
    const int wm = (wave & 1) << 6, wn = (wave >> 1) << 6;
    const int quad = lane >> 4, l16 = lane & 15;

    f32x4 acc[4][4];
#pragma unroll
    for (int i = 0; i < 4; i++)
#pragma unroll
        for (int j = 0; j < 4; j++) acc[i][j] = (f32x4){0.f, 0.f, 0.f, 0.f};

    const int lrA = (wave << 5) + (lane >> 2);
    const int lc  = (lane & 3) << 3;
    int ra0 = m0 + lrA;      if (ra0 > M - 1) ra0 = M - 1;
    int ra1 = m0 + lrA + 16; if (ra1 > M - 1) ra1 = M - 1;
    int rb0 = n0 + lrA;      if (rb0 > N - 1) rb0 = N - 1;
    int rb1 = n0 + lrA + 16; if (rb1 > N - 1) rb1 = N - 1;
    const u16* gA0 = Ab + (long)ra0 * lda + lc;
    const u16* gA1 = Ab + (long)ra1 * lda + lc;
    const u16* gB0 = Bb + (long)rb0 * ldb + lc;
    const u16* gB1 = Bb + (long)rb1 * ldb + lc;
    u16* lA0 = As + ((wave << 5) +  0) * 32;
    u16* lA1 = As + ((wave << 5) + 16) * 32;
    u16* lB0 = Bs + ((wave << 5) +  0) * 32;
    u16* lB1 = Bs + ((wave << 5) + 16) * 32;

    // prologue: stage K-step 0 into buffer 0
    llds16(gA0, lA0);
    llds16(gA1, lA1);
    llds16(gB0, lB0);
    llds16(gB1, lB1);
    __syncthreads();    // compiler drains vmcnt(0) before s_barrier

    int cur = 0;
    for (int k0 = 0; k0 < K; k0 += 32) {
        const int nxt = cur ^ 1;
        // issue next K-step's DMA into the other buffer; it stays in flight
        // across the whole ds_read+MFMA phase below.
        if (k0 + 32 < K) {
            llds16(gA0 + k0 + 32, lA0 + nxt * BUF);
            llds16(gA1 + k0 + 32, lA1 + nxt * BUF);
            llds16(gB0 + k0 + 32, lB0 + nxt * BUF);
            llds16(gB1 + k0 + 32, lB1 + nxt * BUF);
        }

        const u16* Ac = As + cur * BUF;
        const u16* Bc = Bs + cur * BUF;
        bf16x8 af[4], bfr[4];
#pragma unroll
        for (int t = 0; t < 4; t++)
            af[t] = *(const bf16x8*)(Ac + (wm + t * 16 + l16) * 32 + quad * 8);
#pragma unroll
        for (int t = 0; t < 4; t++)
            bfr[t] = *(const bf16x8*)(Bc + (wn + t * 16 + l16) * 32 + quad * 8);
#pragma unroll
        for (int i = 0; i < 4; i++)
#pragma unroll
            for (int j = 0; j < 4; j++)
                acc[i][j] = __builtin_amdgcn_mfma_f32_16x16x32_bf16(
                    af[i], bfr[j], acc[i][j], 0, 0, 0);

        // one barrier per K-step: drains vmcnt (staged tile resident) and
        // lgkmcnt (all waves' ds_reads of cur done) before buffer swap.
        __syncthreads();
        cur = nxt;
    }

#pragma unroll
    for (int j = 0; j < 4; j++) {
        int col  = n0 + wn + j * 16 + l16;
        int colc = col < N ? col : N - 1;
        float bv = bias ? bias[colc] : 0.f;
#pragma unroll
        for (int i = 0; i < 4; i++) {
#pragma unroll
            for (int r = 0; r < 4; r++) {
                int row = m0 + wm + i * 16 + quad * 4 + r;
                float v = acc[i][j][r] * scale + bv;
                if (flags & 1)
                    v = 0.5f * v * (1.f + erff(v * 0.70710678118654752f));
                if (row < M && col < N) {
                    if (Cfb) Cfb[(long)row * ldc + col] = v;
                    else     Cb [(long)row * ldc + col] = f2bf(v);
                }
            }
        }
    }
}

// ---------------------------------------------------------------------------
// Flash attention: O = softmax(scale*Q K^T + mask) V, head dim 64, L = 512.
//   Q: (b, 512, ldq) bf16, head h at cols h*64;  K: (b, 512, ldk) bf16
//   VT: (bh, 64, 512) bf16 (per-head V^T);  O: (b, 512, 1024) bf16
// grid (bh=cb*16, qt=8): bh FAST so the 8 qt-blocks of one head land on the
// SAME XCD (256 % 8 == 0) -> K/VT fetched once per XCD, L2-served after.
// Block: 4 waves, 64 q-rows; K-tile(128x64) + VT-tile(64x128) staged in LDS.
//
// Swapped-operand S^T = mfma(K,Q): each lane's 32 S values belong to ONE
// q-row (q = l16); softmax fully in-register (exp2 domain, v_cvt_pk_bf16).
// ZERO-SHUFFLE PV: key axis permuted by sigma(kk,quad,t) =
// 32kk + 16*(t>>2) + 4*quad + (t&3) so the B-fragment is the lane's own pk
// registers; V's A-fragment reads the same sigma as two b64 LDS loads.
// T14 async-STAGE: next tile's K/V global loads issue before compute.
// ---------------------------------------------------------------------------
__global__ __launch_bounds__(256, 4) void flash_kernel(
    const u16* __restrict__ Q, const u16* __restrict__ K,
    const u16* __restrict__ VT, u16* __restrict__ O,
    const float* __restrict__ mask, int causal, int ldq, int ldk)
{
    __shared__ __align__(16) u16 Ks[128 * 72];    // keys x dims, pad 64->72
    __shared__ __align__(16) u16 Vs[64 * 136];    // dims x keys, pad 128->136
    const int tid  = threadIdx.x;
    const int wave = tid >> 6, lane = tid & 63;
    const int quad = lane >> 4, l16 = lane & 15;
    const int bh = blockIdx.x, qt = blockIdx.y, b = bh >> 4, h = bh & 15;
    const int qbase = qt * 64 + wave * 16;
    const int qrow  = qbase + l16;            // this lane's q row

    // Q fragment (held all kernel).  Used as the MFMA *B* operand:
    // B[k=quad*8+t][n=l16] = Q[qbase+l16][d=quad*8+t]
    const u16* qp = Q + ((long)b * LTOK + qrow) * ldq + h * 64 + quad * 8;
    bf16x8 aq0 = *(const bf16x8*)(qp);
    bf16x8 aq1 = *(const bf16x8*)(qp + 32);

    f32x4 oacc[4];
#pragma unroll
    for (int jd = 0; jd < 4; jd++) oacc[jd] = (f32x4){0.f, 0.f, 0.f, 0.f};
    float m_st = -3.0e38f;      // running max, log2 domain
    float l_st = 0.f;           // running denom

    // staging maps
    const int krow = tid >> 3,       kcol = (tid & 7) << 3;   // K: 32 rows/issue
    const int vrow = tid >> 2,       vcol = (tid & 3) << 3;   // VT: 64 rows, 4x8 cols/issue
    const u16* gK = K + ((long)b * LTOK + krow) * ldk + h * 64 + kcol;
    const u16* gV = VT + ((long)bh * 64 + vrow) * LTOK + vcol;

    const float C1    = 0.125f * 1.44269504088896340736f;   // scale*log2(e)
    const float NEGL2 = -10000.0f * 1.44269504088896340736f;

    const int nkt = causal ? ((qt * 64 + 63) >> 7) + 1 : (LTOK >> 7);

    // ---- prologue: stage tile 0 ----
    u16x8 KR[4], VR[4];
#pragma unroll
    for (int i = 0; i < 4; i++) KR[i] = *(const u16x8*)(gK + (long)(i * 32) * ldk);
#pragma unroll
    for (int i = 0; i < 4; i++) VR[i] = *(const u16x8*)(gV + i * 32);
#pragma unroll
    for (int i = 0; i < 4; i++)
        *(u16x8*)(Ks + (i * 32 + krow) * 72 + kcol) = KR[i];
#pragma unroll
    for (int i = 0; i < 4; i++)
        *(u16x8*)(Vs + vrow * 136 + i * 32 + vcol) = VR[i];
    __syncthreads();

    for (int kt = 0; kt < nkt; kt++) {
        const int k0 = kt << 7;
        const bool more = (kt + 1 < nkt);     // block-uniform

        // T14: issue next tile's global loads now; write to LDS after compute
        if (more) {
            const int kn = k0 + 128;
#pragma unroll
            for (int i = 0; i < 4; i++)
                KR[i] = *(const u16x8*)(gK + (long)(kn + i * 32) * ldk);
#pragma unroll
            for (int i = 0; i < 4; i++)
                VR[i] = *(const u16x8*)(gV + kn + i * 32);
        }

        // S^T = K Q^T : C-layout col = l16 = q, row = key = j*16 + quad*4 + r
        f32x4 s[8];
#pragma unroll
        for (int j = 0; j < 8; j++) {
            bf16x8 bk0 = *(const bf16x8*)(Ks + (j * 16 + l16) * 72 + quad * 8);
            bf16x8 bk1 = *(const bf16x8*)(Ks + (j * 16 + l16) * 72 + 32 + quad * 8);
            f32x4 z = (f32x4){0.f, 0.f, 0.f, 0.f};
            z = __builtin_amdgcn_mfma_f32_16x16x32_bf16(bk0, aq0, z, 0, 0, 0);
            s[j] = __builtin_amdgcn_mfma_f32_16x16x32_bf16(bk1, aq1, z, 0, 0, 0);
        }

        // scale (+mask) in log2 domain; per-lane tile max over this lane's 32 keys
        float tm0 = -3.0e38f, tm1 = -3.0e38f, tm2 = -3.0e38f, tm3 = -3.0e38f;
#pragma unroll
        for (int j = 0; j < 8; j++) {
            if (causal) {
                f32x4 m4 = *(const f32x4*)(mask + (long)b * LTOK + k0 + j * 16 + quad * 4);
#pragma unroll
                for (int r = 0; r < 4; r++) {
                    int key = k0 + j * 16 + quad * 4 + r;
                    // additive mask: (1-mk)*NEG*log2e, mk = key<=q ? mask : 0
                    float ad = (key <= qrow) ? fmaf(m4[r], -NEGL2, NEGL2) : NEGL2;
                    s[j][r] = fmaf(s[j][r], C1, ad);
                }
            } else {
#pragma unroll
                for (int r = 0; r < 4; r++) s[j][r] *= C1;
            }
            tm0 = fmaxf(tm0, s[j][0]); tm1 = fmaxf(tm1, s[j][1]);
            tm2 = fmaxf(tm2, s[j][2]); tm3 = fmaxf(tm3, s[j][3]);
        }
        float tmax = fmaxf(fmaxf(tm0, tm1), fmaxf(tm2, tm3));
        // combine across the 4 quads holding the same q-row
        tmax = fmaxf(tmax, __shfl_xor(tmax, 16));
        tmax = fmaxf(tmax, __shfl_xor(tmax, 32));

        float mnew  = fmaxf(m_st, tmax);
        float alpha = __builtin_amdgcn_exp2f(m_st - mnew);
        m_st = mnew;

        // P = exp2(S - m); pack to bf16 pairs in-register
        float rs0 = 0.f, rs1 = 0.f, rs2 = 0.f, rs3 = 0.f;
        unsigned pk[8][2];
#pragma unroll
        for (int j = 0; j < 8; j++) {
            float p0 = __builtin_amdgcn_exp2f(s[j][0] - mnew);
            float p1 = __builtin_amdgcn_exp2f(s[j][1] - mnew);
            float p2 = __builtin_amdgcn_exp2f(s[j][2] - mnew);
            float p3 = __builtin_amdgcn_exp2f(s[j][3] - mnew);
            rs0 += p0; rs1 += p1; rs2 += p2; rs3 += p3;
            asm("v_cvt_pk_bf16_f32 %0, %1, %2" : "=v"(pk[j][0]) : "v"(p0), "v"(p1));
            asm("v_cvt_pk_bf16_f32 %0, %1, %2" : "=v"(pk[j][1]) : "v"(p2), "v"(p3));
        }
        float rsum = (rs0 + rs1) + (rs2 + rs3);
        rsum += __shfl_xor(rsum, 16);
        rsum += __shfl_xor(rsum, 32);
        l_st = l_st * alpha + rsum;

#pragma unroll
        for (int jd = 0; jd < 4; jd++) oacc[jd] *= alpha;

        // O^T += V^T P^T under key-permutation sigma:
        //   B-frag(lane quad,l16)[t] = P[32kk + 16*(t>>2) + 4*quad + (t&3)][l16]
        //   = this lane's own pk registers -> zero shuffles.
        //   A-frag[t] = Vs[jd*16+l16][same sigma] -> two b64 reads.
#pragma unroll
        for (int kk = 0; kk < 4; kk++) {
            unsigned wv[4] = { pk[2 * kk][0], pk[2 * kk][1],
                               pk[2 * kk + 1][0], pk[2 * kk + 1][1] };
            bf16x8 bp; __builtin_memcpy(&bp, wv, 16);
#pragma unroll
            for (int jd = 0; jd < 4; jd++) {
                const u16* vb = Vs + (jd * 16 + l16) * 136 + kk * 32 + quad * 4;
                u16 va[8];
                *(u16x4*)(va)     = *(const u16x4*)(vb);
                *(u16x4*)(va + 4) = *(const u16x4*)(vb + 16);
                bf16x8 av; __builtin_memcpy(&av, va, 16);
                oacc[jd] = __builtin_amdgcn_mfma_f32_16x16x32_bf16(av, bp, oacc[jd], 0, 0, 0);
            }
        }

        if (more) {
            __syncthreads();    // all waves done reading current Ks/Vs
#pragma unroll
            for (int i = 0; i < 4; i++)
                *(u16x8*)(Ks + (i * 32 + krow) * 72 + kcol) = KR[i];
#pragma unroll
            for (int i = 0; i < 4; i++)
                *(u16x8*)(Vs + vrow * 136 + i * 32 + vcol) = VR[i];
            __syncthreads();
        }
    }

    // O^T element (d = jd*16 + quad*4 + r, q = l16): 4 consecutive cols/lane
    float linv = 1.f / l_st;
    long obase = ((long)b * LTOK + qrow) * DDIM + h * 64;
#pragma unroll
    for (int jd = 0; jd < 4; jd++) {
        u16x4 ov;
#pragma unroll
        for (int r = 0; r < 4; r++) ov[r] = f2bf(oacc[jd][r] * linv);
        *(u16x4*)(O + obase + jd * 16 + quad * 4) = ov;
    }
}

// out = LayerNorm(a + b) * g + beta.  a: bf16.  b: bf16 unless b32 (fp32).
// Output: bf16 (o) unless of != nullptr (fp32).  Row length 1024.
__global__ __launch_bounds__(256) void add_ln_kernel(
    const u16* __restrict__ a, const u16* __restrict__ b,
    const float* __restrict__ b32,
    const float* __restrict__ g, const float* __restrict__ bt,
    u16* __restrict__ o, float* __restrict__ of)
{
    long row = blockIdx.x;
    int tid = threadIdx.x;
    __shared__ float red[4];
    const u16* ar = a + row * DDIM;
    float xv[4]; float s = 0.f;
#pragma unroll
    for (int i = 0; i < 4; i++) {
        int c = tid + 256 * i;
        float sum = bf2f(ar[c]) + (b32 ? b32[row * DDIM + c] : bf2f(b[row * DDIM + c]));
        xv[i] = fminf(fmaxf(sum, -1.0e18f), 1.0e18f);
        s += xv[i];
    }
#pragma unroll
    for (int ofs = 32; ofs >= 1; ofs >>= 1) s += __shfl_xor(s, ofs);
    int wave = tid >> 6, lane = tid & 63;
    if (lane == 0) red[wave] = s;
    __syncthreads();
    float mu = (red[0] + red[1] + red[2] + red[3]) * (1.f / 1024.f);
    __syncthreads();
    float v = 0.f;
#pragma unroll
    for (int i = 0; i < 4; i++) { float d = xv[i] - mu; v += d * d; }
#pragma unroll
    for (int ofs = 32; ofs >= 1; ofs >>= 1) v += __shfl_xor(v, ofs);
    if (lane == 0) red[wave] = v;
    __syncthreads();
    float var = (red[0] + red[1] + red[2] + red[3]) * (1.f / 1024.f);
    float inv = rsqrtf(var + 1e-6f);
#pragma unroll
    for (int i = 0; i < 4; i++) {
        int c = tid + 256 * i;
        float r = (xv[i] - mu) * inv * g[c] + bt[c];
        if (of) of[row * DDIM + c] = r;
        else    o [row * DDIM + c] = f2bf(r);
    }
}

// fp32 -> bf16 conversion, 8 elements/thread.
__global__ __launch_bounds__(256) void cvt_kernel(
    const float* __restrict__ src, u16* __restrict__ dst)
{
    long i = ((long)blockIdx.x * 256 + threadIdx.x) * 8;
    u16x8 o;
#pragma unroll
    for (int j = 0; j < 8; j++) o[j] = f2bf(src[i + j]);
    *(u16x8*)(dst + i) = o;
}

// Transpose+cvt the 8 fp32 weight matrices (1024x1024): WT[n][k] = bf16(W[k][n])
__global__ __launch_bounds__(256) void wt_kernel(
    const float* w0, const float* w1, const float* w2, const float* w3,
    const float* w4, const float* w5, const float* w6, const float* w7,
    u16* __restrict__ wt)
{
    const float* srcs[8] = {w0, w1, w2, w3, w4, w5, w6, w7};
    const float* w = srcs[blockIdx.z];
    u16* o = wt + (long)blockIdx.z * DDIM * DDIM;
    __shared__ u16 t[32][33];
    int tx = threadIdx.x & 31, ty = threadIdx.x >> 5;
    int c0 = blockIdx.x << 5, r0 = blockIdx.y << 5;
#pragma unroll
    for (int i = 0; i < 4; i++)
        t[ty + 8 * i][tx] = f2bf(w[(long)(r0 + ty + 8 * i) * DDIM + c0 + tx]);
    __syncthreads();
#pragma unroll
    for (int i = 0; i < 4; i++)
        o[(long)(c0 + ty + 8 * i) * DDIM + r0 + tx] = t[tx][ty + 8 * i];
}

// Concatenate up to 3 bias vectors (1024 each) into one fp32 array.
__global__ __launch_bounds__(256) void biascat_kernel(
    const float* __restrict__ b0, const float* __restrict__ b1,
    const float* __restrict__ b2, float* __restrict__ dst)
{
    int i = blockIdx.x * 256 + threadIdx.x;
    const float* s = (i < 1024) ? b0 : (i < 2048) ? b1 : b2;
    dst[i] = s[i & 1023];
}

// vt[(b*NH+h)*64 + dd][k] = v[b*LTOK + k][h*64 + dd]   (per-head V transpose)
__global__ __launch_bounds__(256) void vtrans_kernel(
    const u16* __restrict__ v, u16* __restrict__ vt, int ldv)
{
    int bh = blockIdx.y; int b = bh >> 4, h = bh & 15;
    int k0 = blockIdx.x << 5;
    __shared__ __align__(16) u16 t[32 * 72];
    int kk = threadIdx.x >> 3, c = (threadIdx.x & 7) << 3;
    u16x8 val = *(const u16x8*)(v + ((long)b * LTOK + k0 + kk) * ldv + h * 64 + c);
    *(u16x8*)(t + kk * 72 + c) = val;
    __syncthreads();
    int dd = threadIdx.x >> 2, k2 = (threadIdx.x & 3) << 3;
    u16x8 o;
#pragma unroll
    for (int j = 0; j < 8; j++) o[j] = t[(k2 + j) * 72 + dd];
    *(u16x8*)(vt + ((long)bh * 64 + dd) * LTOK + k0 + k2) = o;
}

extern "C" void kernel_launch(void* const* d_in, const int* in_sizes, int n_in,
                              void* d_out, int out_size, void* d_ws, size_t ws_size,
                              hipStream_t stream)
{
    const float* x     = (const float*)d_in[0];
    const float* dmsk  = (const float*)d_in[1];
    const float* enc   = (const float*)d_in[2];
    const float* sa_wq = (const float*)d_in[3];  const float* sa_bq = (const float*)d_in[4];
    const float* sa_wk = (const float*)d_in[5];  const float* sa_bk = (const float*)d_in[6];
    const float* sa_wv = (const float*)d_in[7];  const float* sa_bv = (const float*)d_in[8];
    const float* n1_g  = (const float*)d_in[9];  const float* n1_b  = (const float*)d_in[10];
    const float* ca_wq = (const float*)d_in[11]; const float* ca_bq = (const float*)d_in[12];
    const float* ca_wk = (const float*)d_in[13]; const float* ca_bk = (const float*)d_in[14];
    const float* ca_wv = (const float*)d_in[15]; const float* ca_bv = (const float*)d_in[16];
    const float* n2_g  = (const float*)d_in[17]; const float* n2_b  = (const float*)d_in[18];
    const float* int_w = (const float*)d_in[19]; const float* int_b = (const float*)d_in[20];
    const float* out_w = (const float*)d_in[21]; const float* out_b = (const float*)d_in[22];
    const float* out_g = (const float*)d_in[23]; const float* out_bt= (const float*)d_in[24];

    float* outp = (float*)d_out;
    float* visp = outp + (long)NBATCH * LTOK * DDIM;   // attention_vis (fp32)

    // --- workspace: chunk over batches; 7 buffer units / batch + WT + bias ---
    const size_t WTB  = (size_t)8 * DDIM * DDIM * 2;            // 16 MiB
    const size_t BUF1 = (size_t)LTOK * DDIM * 2;                // 1 MiB / batch
    int cb = 16;
    while (cb > 1 && WTB + (size_t)cb * 7 * BUF1 + 32768 > ws_size)
        cb >>= 1;

    char* ws = (char*)d_ws;
    size_t off = 0;
    auto alloc = [&](size_t bytes) -> u16* {
        u16* p = (u16*)(ws + off);
        off += (bytes + 255) & ~(size_t)255;
        return p;
    };
    u16* Xb  = alloc((size_t)cb * BUF1);          // Xb -> h
    u16* Eb  = alloc((size_t)cb * BUF1);          // Eb -> h2
    u16* Q3  = alloc((size_t)cb * 3 * BUF1);      // qkv(ld 3072) -> CQ | CKV -> I | G
    u16* Vt  = alloc((size_t)cb * BUF1);          // per-head V^T (self, then cross)
    u16* Cx  = alloc((size_t)cb * BUF1);          // attn ctx (self, then cross)
    u16* WT  = alloc(WTB);
    float* biasQKV = (float*)alloc(3072 * sizeof(float));
    float* biasKV  = (float*)alloc(2048 * sizeof(float));
    // no memset needed: every region fully written before read.

    u16* Wsaq = WT + 0L * DDIM * DDIM;   // [Wsaq|Wsak|Wsav] contiguous => fused B
    u16* Wcaq = WT + 3L * DDIM * DDIM;
    u16* Wcak = WT + 4L * DDIM * DDIM;   // [Wcak|Wcav] contiguous => fused B
    u16* Wint = WT + 6L * DDIM * DDIM;
    u16* Wout = WT + 7L * DDIM * DDIM;

    auto gemm = [&](const u16* A, int lda, long sA1, long sA2,
                    const u16* B, int ldb, long sB1, long sB2,
                    u16* C, float* Cf, int ldc, long sC1, long sC2,
                    int M, int N, int K, int Z, int zdiv,
                    const float* bias, float scale, int flags) {
        int tM = (M + 127) / 128, tN = (N + 127) / 128;
        gemm_bt_kernel<<<dim3(tM * tN, Z), dim3(256), 0, stream>>>(
            A, lda, sA1, sA2, B, ldb, sB1, sB2, C, Cf, ldc, sC1, sC2,
            M, N, K, zdiv, bias, scale, flags);
    };

    const long SLD = (long)LTOK * DDIM;       // per-batch row-block stride
    const long SSC = (long)LTOK * LTOK;       // vis elems per batch

    // 0) weight transposes + bf16 cvt + bias packs (once per call)
    wt_kernel<<<dim3(32, 32, 8), dim3(256), 0, stream>>>(
        sa_wq, sa_wk, sa_wv, ca_wq, ca_wk, ca_wv, int_w, out_w, WT);
    biascat_kernel<<<dim3(12), dim3(256), 0, stream>>>(sa_bq, sa_bk, sa_bv, biasQKV);
    biascat_kernel<<<dim3(8),  dim3(256), 0, stream>>>(ca_bk, ca_bv, ca_bv, biasKV);

    for (int b0 = 0; b0 < NBATCH; b0 += cb) {
        const float* xc = x   + (long)b0 * SLD;
        const float* ec = enc + (long)b0 * SLD;
        const int M = cb * LTOK;
        const int Z = cb * NH;
        const int cvtg = (int)(((long)M * DDIM) / (256 * 8));

        u16* h   = Xb;                                   // after QKV proj
        u16* CQ  = Q3;                                   // after self-attn
        u16* CKV = Q3 + (size_t)cb * LTOK * DDIM;        // cross k|v, ld 2048
        u16* I   = Q3;                                   // after cross-attn
        u16* G   = Q3 + (size_t)cb * LTOK * DDIM;
        u16* h2  = Eb;                                   // after cross proj

        // a) fp32 -> bf16 activation copies
        cvt_kernel<<<dim3(cvtg), dim3(256), 0, stream>>>(xc, Xb);
        cvt_kernel<<<dim3(cvtg), dim3(256), 0, stream>>>(ec, Eb);

        // 1) fused self-attn q|k|v projection: N=3072, ld 3072 (1536 blocks)
        gemm(Xb, DDIM, 0, 0, Wsaq, DDIM, 0, 0, Q3, nullptr, 3 * DDIM, 0, 0,
             M, 3 * DDIM, DDIM, 1, 1, biasQKV, 1.f, 0);
        vtrans_kernel<<<dim3(16, Z), dim3(256), 0, stream>>>(Q3 + 2 * DDIM, Vt, 3 * DDIM);

        // 2) self-attention (flash, causal+padding), ctx -> Cx
        flash_kernel<<<dim3(Z, 8), dim3(256), 0, stream>>>(
            Q3, Q3 + DDIM, Vt, Cx, dmsk + (long)b0 * LTOK, 1, 3 * DDIM, 3 * DDIM);

        // 3) h = LN(ctx + x_fp32) -> h (Xb reuse)
        add_ln_kernel<<<dim3(M), dim3(256), 0, stream>>>(
            Cx, nullptr, xc, n1_g, n1_b, h, nullptr);

        // 4) cq -> CQ;  fused cross k|v -> CKV (N=2048, ld 2048, 1024 blocks)
        gemm(h, DDIM, 0, 0, Wcaq, DDIM, 0, 0, CQ, nullptr, DDIM, 0, 0,
             M, DDIM, DDIM, 1, 1, ca_bq, 1.f, 0);
        gemm(Eb, DDIM, 0, 0, Wcak, DDIM, 0, 0, CKV, nullptr, 2 * DDIM, 0, 0,
             M, 2 * DDIM, DDIM, 1, 1, biasKV, 1.f, 0);

        // 5) attention_vis = (cq @ ck^T) / 128  -> fp32 d_out
        gemm(CQ, DDIM, SLD, 0, CKV, 2 * DDIM, (long)LTOK * 2 * DDIM, 0,
             nullptr, visp + (long)b0 * SSC, LTOK, SSC, 0,
             LTOK, LTOK, DDIM, cb, 1, nullptr, 1.f / 128.f, 0);

        // 6) cross-attention (flash, no mask): vt(cv)->Vt; ctx -> Cx
        vtrans_kernel<<<dim3(16, Z), dim3(256), 0, stream>>>(CKV + DDIM, Vt, 2 * DDIM);
        flash_kernel<<<dim3(Z, 8), dim3(256), 0, stream>>>(
            CQ, CKV, Vt, Cx, nullptr, 0, DDIM, 2 * DDIM);

        // 7) h2 = LN(h + cactx) -> h2 (Eb reuse)
        add_ln_kernel<<<dim3(M), dim3(256), 0, stream>>>(
            h, Cx, nullptr, n2_g, n2_b, h2, nullptr);

        // 8) inter = gelu(h2 @ int_w + int_b) -> I
        gemm(h2, DDIM, 0, 0, Wint, DDIM, 0, 0, I, nullptr, DDIM, 0, 0,
             M, DDIM, DDIM, 1, 1, int_b, 1.f, 1);
        // 9) G = inter @ out_w + out_b -> G
        gemm(I, DDIM, 0, 0, Wout, DDIM, 0, 0, G, nullptr, DDIM, 0, 0,
             M, DDIM, DDIM, 1, 1, out_b, 1.f, 0);
        // 10) out = LN(G + inter) -> fp32 d_out
        add_ln_kernel<<<dim3(M), dim3(256), 0, stream>>>(
            G, I, nullptr, out_g, out_bt, nullptr, outp + (long)b0 * SLD);
    }
}